// Round 4
// baseline (320.148 us; speedup 1.0000x reference)
//
#include <hip/hip_runtime.h>
#include <hip/hip_bf16.h>

typedef unsigned short u16;
typedef unsigned int u32;
typedef unsigned long long u64;
typedef __attribute__((ext_vector_type(8))) short s16x8;
typedef __attribute__((ext_vector_type(4))) u32 u32x4;
typedef __attribute__((ext_vector_type(4))) float f32x4;
typedef __attribute__((ext_vector_type(16))) float f32x16;

#define SCL 0.1803368867f   // 0.125 * log2(e): exp(s/8) = 2^(s*SCL)

#if __has_builtin(__builtin_amdgcn_exp2f)
#define EXP2(x) __builtin_amdgcn_exp2f(x)
#else
#define EXP2(x) exp2f(x)
#endif

__device__ __forceinline__ float bf2f(u16 v){ u32 u = ((u32)v)<<16; return __builtin_bit_cast(float,u); }
__device__ __forceinline__ u16 f2bf(float f){
  u32 u = __builtin_bit_cast(u32,f);
  u += 0x7fff + ((u>>16)&1);
  return (u16)(u>>16);
}
__device__ __forceinline__ u32 pkbf(float a, float b){   // pack 2 bf16
  u32 ua = __builtin_bit_cast(u32,a) + 0x8000u;
  u32 ub = __builtin_bit_cast(u32,b) + 0x8000u;
  return (ua>>16) | (ub & 0xFFFF0000u);
}
// async global->LDS, 16B per lane; lds_u MUST be wave-uniform (HW adds lane*16)
__device__ __forceinline__ void glds16(const u16* g, const u16* lds_u){
  __builtin_amdgcn_global_load_lds(
      (const __attribute__((address_space(1))) void*)(u64)g,
      (__attribute__((address_space(3))) void*)(u32)(u64)lds_u,
      16, 0, 0);
}
__device__ __forceinline__ f32x4 mfma16(s16x8 a, s16x8 b, f32x4 c){
  return __builtin_amdgcn_mfma_f32_16x16x32_bf16(a,b,c,0,0,0);
}
__device__ __forceinline__ f32x16 mfma32(s16x8 a, s16x8 b, f32x16 c){
  return __builtin_amdgcn_mfma_f32_32x32x16_bf16(a,b,c,0,0,0);
}

// ---------------------------------------------------------------------------
// dtype probe (validated rounds 2-11)
// ---------------------------------------------------------------------------
__global__ __launch_bounds__(256) void detect_dtype(const u16* __restrict__ x, u32* __restrict__ flag){
  __shared__ int cnt;
  if (threadIdx.x==0) cnt = 0;
  __syncthreads();
  int local = 0;
  for (int i = threadIdx.x; i < 4096; i += 256){
    u16 v = x[2*i];
    int e = (v>>7)&0xFF;
    if (e >= 140 || e <= 100) local++;
  }
  atomicAdd(&cnt, local);
  __syncthreads();
  if (threadIdx.x==0) *flag = (cnt > 1024) ? 1u : 0u;
}

struct CvtArgs { const void* src[10]; u16* dst[10]; int n[10]; };

// ---------------------------------------------------------------------------
// Merged weight/bias convert (y<10) + x convert-transpose (y==10).
// Grid (2048, 11), block 256.
// ---------------------------------------------------------------------------
__global__ __launch_bounds__(256) void convert_all(
    CvtArgs a, const void* __restrict__ xsrc,
    const u32* __restrict__ flag, u16* __restrict__ xT)
{
  __shared__ u16 T[64][72];
  const int t = threadIdx.x;
  if (blockIdx.y < 10){
    const int which = blockIdx.y;
    const int n = a.n[which];
    const int base = blockIdx.x*2048 + t;
    if (base >= n) return;
    u16* dst = a.dst[which];
    if (*flag){
      const float* s = (const float*)a.src[which];
      #pragma unroll
      for (int j=0;j<8;j++){ int i = base + j*256; if (i<n) dst[i] = f2bf(s[i]); }
    } else {
      const u16* s = (const u16*)a.src[which];
      #pragma unroll
      for (int j=0;j<8;j++){ int i = base + j*256; if (i<n) dst[i] = s[i]; }
    }
    return;
  }
  // ---- x transpose: xT[b][c][s] = cvt(x[b][s][c]) ----
  const int bx = blockIdx.x;
  if (bx >= 1024) return;
  const int s0 = (bx&31)*64, c0 = ((bx>>5)&15)*64, b = bx>>9;
  const int r = t>>2, cc = (t&3)*16;
  const long off = ((long)(b*2048 + s0 + r))*1024 + c0 + cc;
  if (*flag){
    const float* p = (const float*)xsrc + off;
    #pragma unroll
    for (int j=0;j<16;j++) T[r][cc+j] = f2bf(p[j]);
  } else {
    const u16* p = (const u16*)xsrc + off;
    *(s16x8*)&T[r][cc]   = *(const s16x8*)p;
    *(s16x8*)&T[r][cc+8] = *(const s16x8*)(p+8);
  }
  __syncthreads();
  {
    const int orow = t&63, oc = (t>>6)*16;
    u16 tmp[16];
    #pragma unroll
    for (int j=0;j<16;j++) tmp[j] = T[oc+j][orow];
    u16* q = xT + (long)b*2097152 + (long)(c0+orow)*2048 + s0 + oc;
    *(s16x8*)q     = *(s16x8*)&tmp[0];
    *(s16x8*)(q+8) = *(s16x8*)&tmp[8];
  }
}

// ---------------------------------------------------------------------------
// sv[row] = sum_k Mt[row][k]  (softmax rows sum to 1 => equals sum_t v[b,t,c]).
// Grid 512, block 256 (4 waves, 1 Mt-row each).
// ---------------------------------------------------------------------------
__global__ __launch_bounds__(256) void rowsum_mt(const u16* __restrict__ Mt, float* __restrict__ sv){
  const int row = blockIdx.x*4 + (threadIdx.x>>6);
  const int lane = threadIdx.x&63;
  const u16* p = Mt + (long)row*2048;
  float s = 0.f;
  #pragma unroll
  for (int i=0;i<4;i++){
    s16x8 v = *(const s16x8*)&p[i*512 + lane*8];
    #pragma unroll
    for (int j=0;j<8;j++) s += bf2f((u16)v[j]);
  }
  #pragma unroll
  for (int off=32; off>=1; off>>=1) s += __shfl_xor(s, off);
  if (lane==0) sv[row] = s;
}

// ---------------------------------------------------------------------------
// NT GEMM, BM=128 x BN tile, BK=32, double-buffered LDS + global_load_lds(16B).
// (round-5/7 version — proven)
// ---------------------------------------------------------------------------
template<int BN, int BMODE, bool DYN, bool QS>
__global__ __launch_bounds__(256) void gemm_t(
    const u16* __restrict__ A, const u16* __restrict__ B,
    const u16* __restrict__ bias, const float* __restrict__ r1col,
    const u32* __restrict__ dflag, void* __restrict__ C,
    int K, int lda, int ldb, int ldc,
    long aBatch, long bBatch, long cBatch)
{
  constexpr int BM = 128;
  constexpr int ACH = BM/64, BCH = BN/64;
  constexpr int MI = (BN==128) ? 4 : 2;
  __shared__ u16 As[2][BM*32];
  __shared__ u16 Bs[2][BN*32];
  const int t = threadIdx.x, w = t>>6, quad = (t&63)>>4, l16 = t&15;
  const int z = blockIdx.z;
  const int m0 = blockIdx.x*BM, n0 = blockIdx.y*BN;
  const u16* Ag = A + (long)z*aBatch + (long)m0*lda;
  const u16* Bg = B + (long)z*bBatch + (long)n0*ldb;
  const int wm = (BN==128) ? (w>>1)*64 : w*32;
  const int wn = (BN==128) ? (w&1)*64 : 0;

  auto stage = [&](int buf, int k0){
    #pragma unroll
    for (int i=0;i<ACH;i++){
      const int chunk = i*256 + t;
      glds16(Ag + (long)(chunk>>2)*lda + k0 + (chunk&3)*8, &As[buf][(i*256 + w*64)*8]);
    }
    #pragma unroll
    for (int i=0;i<BCH;i++){
      const int chunk = i*256 + t;
      glds16(Bg + (long)(chunk>>2)*ldb + k0 + (chunk&3)*8, &Bs[buf][(i*256 + w*64)*8]);
    }
  };

  f32x4 acc[MI][4];
  #pragma unroll
  for (int i=0;i<MI;i++)
    #pragma unroll
    for (int j=0;j<4;j++) acc[i][j] = (f32x4){0.f,0.f,0.f,0.f};

  stage(0, 0);
  const int nk = K>>5;
  for (int kt=0; kt<nk; ++kt){
    __syncthreads();
    if (kt+1 < nk) stage((kt+1)&1, (kt+1)<<5);
    const u16* as = As[kt&1];
    const u16* bs = Bs[kt&1];
    s16x8 a[MI], bb[4];
    #pragma unroll
    for (int i=0;i<MI;i++) a[i] = *(const s16x8*)&as[(wm + i*16 + l16)*32 + quad*8];
    #pragma unroll
    for (int j=0;j<4;j++)  bb[j]= *(const s16x8*)&bs[(wn + j*16 + l16)*32 + quad*8];
    #pragma unroll
    for (int i=0;i<MI;i++)
      #pragma unroll
      for (int j=0;j<4;j++)
        acc[i][j] = mfma16(a[i], bb[j], acc[i][j]);
  }

  bool f32o = false;
  if (DYN) f32o = (*dflag != 0);
  #pragma unroll
  for (int i=0;i<MI;i++){
    #pragma unroll
    for (int j=0;j<4;j++){
      const int col = n0 + wn + j*16 + l16;
      #pragma unroll
      for (int r=0;r<4;r++){
        const int row = m0 + wm + i*16 + quad*4 + r;
        float vv = acc[i][j][r];
        if (BMODE==1) vv += bf2f(bias[row]);
        if (BMODE==2) vv += bf2f(bias[col]);
        if (BMODE==3) vv += bf2f(bias[row]) * r1col[z*1024 + col];
        if (QS){ if (col < 1024) vv *= SCL; }
        const long idx = (long)z*cBatch + (long)row*ldc + col;
        if (DYN && f32o) ((float*)C)[idx] = vv;
        else             ((u16*)C)[idx]   = f2bf(vv);
      }
    }
  }
}

// ---------------------------------------------------------------------------
// Fused softmax-denominator + V-scale-transpose (R12 version — proven).
// ---------------------------------------------------------------------------
__global__ __launch_bounds__(256) void attn_stats(const u16* __restrict__ qkv, u16* __restrict__ VtG){
  __shared__ u16 Qs[64][68];
  __shared__ u16 Ks[64][68];
  __shared__ float red[2][64];
  __shared__ float ilv[64];
  const int q0 = blockIdx.x*64, bh = blockIdx.y, b = bh>>4, h = bh&15;
  const int t = threadIdx.x, w = t>>6, l32 = t&31, half = (t&63)>>5;
  const int wq = w>>1, wk = w&1;
  const int r = t>>2, cc = (t&3)*16;
  {
    const u16* p = &qkv[((long)(b*2048 + q0 + r))*3072 + h*64 + cc];
    *(s16x8*)&Qs[r][cc]   = *(const s16x8*)p;
    *(s16x8*)&Qs[r][cc+8] = *(const s16x8*)(p+8);
  }
  // prefetch K tile 0 into regs (overlaps with Q staging + barrier)
  const u16* kg = &qkv[((long)(b*2048 + r))*3072 + 1024 + h*64 + cc];
  s16x8 sk0 = *(const s16x8*)kg;
  s16x8 sk1 = *(const s16x8*)(kg+8);
  __syncthreads();
  s16x8 aq[4];
  #pragma unroll
  for (int u=0;u<4;u++) aq[u] = *(s16x8*)&Qs[wq*32 + l32][u*16 + half*8];
  float lp[16];
  #pragma unroll
  for (int r2=0;r2<16;r2++) lp[r2] = 0.f;

  for (int kc=0; kc<2048; kc+=64){
    __syncthreads();                           // prev Ks reads done
    *(s16x8*)&Ks[r][cc]   = sk0;
    *(s16x8*)&Ks[r][cc+8] = sk1;
    __syncthreads();                           // Ks visible
    if (kc+64 < 2048){                         // issue next-tile loads early
      const u16* nk = kg + (long)(kc+64)*3072;
      sk0 = *(const s16x8*)nk;
      sk1 = *(const s16x8*)(nk+8);
    }
    s16x8 kb[4];
    #pragma unroll
    for (int u=0;u<4;u++) kb[u] = *(s16x8*)&Ks[wk*32 + l32][u*16 + half*8];
    f32x16 acc = {};
    #pragma unroll
    for (int u=0;u<4;u++) acc = mfma32(aq[u], kb[u], acc);
    #pragma unroll
    for (int r2=0;r2<16;r2++) lp[r2] += EXP2(acc[r2]);
  }
  #pragma unroll
  for (int off=1; off<32; off<<=1)
    #pragma unroll
    for (int r2=0;r2<16;r2++) lp[r2] += __shfl_xor(lp[r2], off);
  if (l32 == 0){
    #pragma unroll
    for (int r2=0;r2<16;r2++)
      red[wk][wq*32 + 4*half + (r2&3) + 8*(r2>>2)] = lp[r2];
  }
  __syncthreads();
  if (t < 64) ilv[t] = 1.f / (red[0][t] + red[1][t]);
  __syncthreads();
  // ---- fused V scale+transpose through Qs (dead after aq) ----
  {
    const u16* p = &qkv[((long)(b*2048 + q0 + r))*3072 + 2048 + h*64 + cc];
    const float sc = ilv[r];
    s16x8 v0 = *(const s16x8*)p, v1 = *(const s16x8*)(p+8);
    #pragma unroll
    for (int j=0;j<8;j++){
      Qs[r][cc+j]   = f2bf(bf2f((u16)v0[j])*sc);
      Qs[r][cc+8+j] = f2bf(bf2f((u16)v1[j])*sc);
    }
  }
  __syncthreads();
  {
    const int orow = t&63, oc = (t>>6)*16;
    u16 tmp[16];
    #pragma unroll
    for (int j=0;j<16;j++) tmp[j] = Qs[oc+j][orow];
    u16* q = VtG + (long)b*2097152 + (long)(h*64+orow)*2048 + q0 + oc;
    *(s16x8*)q     = *(s16x8*)&tmp[0];
    *(s16x8*)(q+8) = *(s16x8*)&tmp[8];
  }
}

// ---------------------------------------------------------------------------
// Mt[b, h*64+d, k] = sum_q exp2(q'.k) * vtilde[d,q]   (V pre-scaled by il[q]).
// R15: split-q occupancy. 4 waves = 2 kcol-groups x 2 q-halves; each wave
// owns 32 kcols x full 64-q tile (R14's wave-private P via permlane32_swap),
// q-halves sum 16 tiles each into f32 accM, combined once through LDS.
// cvt_pk_bf16_f32 replaces the 5-instr manual pack. Grid (32,32), block 256
// = 1024 blocks = 4/CU = 4 waves/SIMD.  LDS 34.8 KB.
// ---------------------------------------------------------------------------
__global__ __launch_bounds__(256,4) void attn_pv(
    const u16* __restrict__ qkv, const u16* __restrict__ VtG, u16* __restrict__ Mt)
{
  __shared__ u16 Qs[2][64][68];
  __shared__ u16 Vs[2][64][68];
  const int t = threadIdx.x, w = t>>6, l32 = t&31, hi = (t&63)>>5;
  const int kg = w&1, qh = w>>1;
  const int bh = blockIdx.y, b = bh>>4, h = bh&15;
  const int kcol = blockIdx.x*64 + kg*32 + l32;
  const int r = t>>2, cc = (t&3)*16;

  // K fragments (B-op of QK): lane holds K[kcol][d = c*16 + hi*8 + j].
  // One-time uncoalesced global load (L2-cached), persistent in regs.
  const u16* kp = qkv + ((long)(b*2048 + kcol))*3072 + 1024 + h*64 + hi*8;
  s16x8 kb[4];
  #pragma unroll
  for (int c=0;c<4;c++) kb[c] = *(const s16x8*)(kp + c*16);

  // coalesced staging pointers: thread loads row r, cols cc..cc+15,
  // for BOTH q-halves (half1 = half0 + 1024 rows/cols).
  const u16* qg = &qkv[((long)(b*2048 + r))*3072 + h*64 + cc];
  const u16* vg = &VtG[((long)(b*1024 + h*64 + r))*2048 + cc];
  s16x8 q0a = *(const s16x8*)qg,      q0b = *(const s16x8*)(qg+8);
  s16x8 q1a = *(const s16x8*)(qg + (long)1024*3072), q1b = *(const s16x8*)(qg + (long)1024*3072 + 8);
  s16x8 v0a = *(const s16x8*)vg,      v0b = *(const s16x8*)(vg+8);
  s16x8 v1a = *(const s16x8*)(vg + 1024), v1b = *(const s16x8*)(vg + 1024 + 8);

  f32x16 accM0 = {}, accM1 = {};
  for (int i=0; i<16; ++i){
    __syncthreads();                           // prev Qs/Vs reads done
    *(s16x8*)&Qs[0][r][cc]   = q0a;  *(s16x8*)&Qs[0][r][cc+8] = q0b;
    *(s16x8*)&Qs[1][r][cc]   = q1a;  *(s16x8*)&Qs[1][r][cc+8] = q1b;
    *(s16x8*)&Vs[0][r][cc]   = v0a;  *(s16x8*)&Vs[0][r][cc+8] = v0b;
    *(s16x8*)&Vs[1][r][cc]   = v1a;  *(s16x8*)&Vs[1][r][cc+8] = v1b;
    __syncthreads();                           // Qs/Vs visible
    if (i+1 < 16){                             // T14: issue next-tile loads early
      const u16* nq = qg + (long)(i+1)*64*3072;
      const u16* nv = vg + (i+1)*64;
      q0a = *(const s16x8*)nq;  q0b = *(const s16x8*)(nq+8);
      q1a = *(const s16x8*)(nq + (long)1024*3072); q1b = *(const s16x8*)(nq + (long)1024*3072 + 8);
      v0a = *(const s16x8*)nv;  v0b = *(const s16x8*)(nv+8);
      v1a = *(const s16x8*)(nv + 1024); v1b = *(const s16x8*)(nv + 1024 + 8);
    }
    // fragments from this wave's q-half tile (full 64-q range, own 32 kcols)
    s16x8 aq0[4], aq1[4];
    #pragma unroll
    for (int c=0;c<4;c++){
      aq0[c] = *(s16x8*)&Qs[qh][l32][c*16 + hi*8];
      aq1[c] = *(s16x8*)&Qs[qh][32+l32][c*16 + hi*8];
    }
    f32x16 acc0 = {}, acc1 = {};
    #pragma unroll
    for (int c=0;c<4;c++){
      acc0 = mfma32(aq0[c], kb[c], acc0);
      acc1 = mfma32(aq1[c], kb[c], acc1);
    }
    // exp -> cvt_pk_bf16 -> permlane32_swap: PV B-fragments in-register
    // (R13-verified layout). C/D: lane holds P[q = qt*32 + (r&3)+8*(r>>2)+4*hi][kcol];
    // B-frag bp[c] needs P[q = c*16 + 8*hi + j][kcol].
    s16x8 bp[4];
    #pragma unroll
    for (int qt=0;qt<2;qt++){
      float p[16];
      #pragma unroll
      for (int r2=0;r2<16;r2++) p[r2] = EXP2(qt ? acc1[r2] : acc0[r2]);
      #pragma unroll
      for (int ccc=0; ccc<2; ccc++){
        u32 X0, X1, Y0, Y1;
        asm("v_cvt_pk_bf16_f32 %0, %1, %2" : "=v"(X0) : "v"(p[ccc*8+0]), "v"(p[ccc*8+1]));
        asm("v_cvt_pk_bf16_f32 %0, %1, %2" : "=v"(X1) : "v"(p[ccc*8+2]), "v"(p[ccc*8+3]));
        asm("v_cvt_pk_bf16_f32 %0, %1, %2" : "=v"(Y0) : "v"(p[ccc*8+4]), "v"(p[ccc*8+5]));
        asm("v_cvt_pk_bf16_f32 %0, %1, %2" : "=v"(Y1) : "v"(p[ccc*8+6]), "v"(p[ccc*8+7]));
        asm volatile("v_permlane32_swap_b32 %0, %1" : "+v"(X0), "+v"(Y0));
        asm volatile("v_permlane32_swap_b32 %0, %1" : "+v"(X1), "+v"(Y1));
        u32x4 dw; dw[0]=X0; dw[1]=X1; dw[2]=Y0; dw[3]=Y1;
        bp[qt*2+ccc] = __builtin_bit_cast(s16x8, dw);
      }
    }
    // PV: accM[i] covers d = i*32..+32 x k = kcol, contraction over this q-tile
    s16x8 av0[4], av1[4];
    #pragma unroll
    for (int c=0;c<4;c++){
      av0[c] = *(s16x8*)&Vs[qh][l32][c*16 + hi*8];
      av1[c] = *(s16x8*)&Vs[qh][32+l32][c*16 + hi*8];
    }
    #pragma unroll
    for (int c=0;c<4;c++){
      accM0 = mfma32(av0[c], bp[c], accM0);
      accM1 = mfma32(av1[c], bp[c], accM1);
    }
  }
  // ---- combine q-halves through LDS (lane-contiguous layout, no conflicts) ----
  float* red = (float*)&Qs[0][0][0];           // 32*128 floats = 16 KB <= 17.4 KB
  const int lane = t&63;
  __syncthreads();                             // all tile reads done
  if (qh == 1){
    #pragma unroll
    for (int r2=0;r2<16;r2++){
      red[r2*128      + kg*64 + lane] = accM0[r2];
      red[(16+r2)*128 + kg*64 + lane] = accM1[r2];
    }
  }
  __syncthreads();
  if (qh == 0){
    #pragma unroll
    for (int r2=0;r2<16;r2++){
      const int d0 = 4*hi + (r2&3) + 8*(r2>>2);
      const float m0 = accM0[r2] + red[r2*128      + kg*64 + lane];
      const float m1 = accM1[r2] + red[(16+r2)*128 + kg*64 + lane];
      Mt[((long)(b*1024 + h*64 + d0))*2048 + kcol]      = f2bf(m0);
      Mt[((long)(b*1024 + h*64 + d0 + 32))*2048 + kcol] = f2bf(m1);
    }
  }
}

extern "C" void kernel_launch(void* const* d_in, const int* in_sizes, int n_in,
                              void* d_out, int out_size, void* d_ws, size_t ws_size,
                              hipStream_t stream)
{
  (void)n_in; (void)out_size; (void)ws_size;
  char* ws = (char*)d_ws;
  u32*  dflag = (u32*)ws;            ws += 64;
  u16*  whc   = (u16*)ws;            ws += (size_t)8388608;
  u16*  wqkvc = (u16*)ws;            ws += (size_t)6291456;
  u16*  woc   = (u16*)ws;            ws += (size_t)8388608;
  u16*  bhc   = (u16*)ws;            ws += 4096;
  u16*  bqkvc = (u16*)ws;            ws += 8192;
  u16*  boc   = (u16*)ws;            ws += 4096;
  u16*  xT    = (u16*)ws;            ws += (size_t)8388608;
  u16*  xh    = (u16*)ws;            ws += (size_t)8388608;
  u16*  qkvb  = (u16*)ws;            ws += (size_t)25165824;
  u16*  VtG   = (u16*)ws;            ws += (size_t)8388608;
  u16*  Mt    = (u16*)ws;            ws += (size_t)8388608;
  float* sv   = (float*)ws;          ws += 8192;

  // 0) probe dtype + canonicalize all inputs (weights/biases + x-transpose fused)
  detect_dtype<<<1,256,0,stream>>>((const u16*)d_in[0], dflag);
  CvtArgs ca;
  const void* srcs[10] = {d_in[1], d_in[2], d_in[3], d_in[4], d_in[5],
                          d_in[6], d_in[7], d_in[8], d_in[9], d_in[10]};
  u16* dsts[10] = {whc, bhc, wqkvc, bqkvc, wqkvc+1048576, bqkvc+1024,
                   wqkvc+2097152, bqkvc+2048, woc, boc};
  const int ns[10] = {in_sizes[1], in_sizes[2], in_sizes[3], in_sizes[4], in_sizes[5],
                      in_sizes[6], in_sizes[7], in_sizes[8], in_sizes[9], in_sizes[10]};
  for (int i=0;i<10;i++){ ca.src[i]=srcs[i]; ca.dst[i]=dsts[i]; ca.n[i]=ns[i]; }
  convert_all<<<dim3(2048,11),256,0,stream>>>(ca, d_in[0], dflag, xT);

  const long S2M = 2097152L;   // 2048*1024

  // 1) xh = w_hseq @ xT^T + b_hseq   (NT, row bias)
  gemm_t<64,1,false,false><<<dim3(16,16,2),256,0,stream>>>(whc, xT, bhc, nullptr, dflag, xh,
      2048, 2048, 2048, 1024, 0L, S2M, S2M);

  // 2) qkv = xh @ Wqkv^T + bqkv; q-columns pre-scaled by SCL   (NT, col bias)
  gemm_t<128,2,false,true><<<dim3(16,24,2),256,0,stream>>>(xh, wqkvc, bqkvc, nullptr, dflag, qkvb,
      1024, 1024, 1024, 3072, S2M, 0L, (long)2048*3072);

  // 3) softmax denominators + fused V scale-transpose -> VtG
  attn_stats<<<dim3(32,32),256,0,stream>>>(qkvb, VtG);

  // 4) Mt = (attn^T @ v)^T   (R15: split-q, 4 waves/SIMD, in-register P)
  attn_pv<<<dim3(32,32),256,0,stream>>>(qkvb, VtG, Mt);

  // 5) sv[b,c] = sum_k Mt[b,c,k]  (softmax rows sum to 1 => = sum_t v[b,t,c])
  rowsum_mt<<<512,256,0,stream>>>(Mt, sv);

  // 6) out = w_oseq @ Mt^T + b_oseq (x) sv   (NT, rank-1 bias, dyn dtype)
  gemm_t<64,3,true,false><<<dim3(16,16,2),256,0,stream>>>(woc, Mt, boc, sv, dflag, d_out,
      2048, 2048, 2048, 1024, 0L, S2M, S2M);
}

// Round 5
// 310.384 us; speedup vs baseline: 1.0315x; 1.0315x over previous
//
#include <hip/hip_runtime.h>
#include <hip/hip_bf16.h>

typedef unsigned short u16;
typedef unsigned int u32;
typedef unsigned long long u64;
typedef __attribute__((ext_vector_type(8))) short s16x8;
typedef __attribute__((ext_vector_type(4))) u32 u32x4;
typedef __attribute__((ext_vector_type(4))) float f32x4;
typedef __attribute__((ext_vector_type(16))) float f32x16;

#define SCL 0.1803368867f   // 0.125 * log2(e): exp(s/8) = 2^(s*SCL)

#if __has_builtin(__builtin_amdgcn_exp2f)
#define EXP2(x) __builtin_amdgcn_exp2f(x)
#else
#define EXP2(x) exp2f(x)
#endif

__device__ __forceinline__ float bf2f(u16 v){ u32 u = ((u32)v)<<16; return __builtin_bit_cast(float,u); }
__device__ __forceinline__ u16 f2bf(float f){
  u32 u = __builtin_bit_cast(u32,f);
  u += 0x7fff + ((u>>16)&1);
  return (u16)(u>>16);
}
__device__ __forceinline__ u32 pkbf(float a, float b){   // pack 2 bf16
  u32 ua = __builtin_bit_cast(u32,a) + 0x8000u;
  u32 ub = __builtin_bit_cast(u32,b) + 0x8000u;
  return (ua>>16) | (ub & 0xFFFF0000u);
}
// async global->LDS, 16B per lane; lds_u MUST be wave-uniform (HW adds lane*16)
__device__ __forceinline__ void glds16(const u16* g, const u16* lds_u){
  __builtin_amdgcn_global_load_lds(
      (const __attribute__((address_space(1))) void*)(u64)g,
      (__attribute__((address_space(3))) void*)(u32)(u64)lds_u,
      16, 0, 0);
}
__device__ __forceinline__ f32x4 mfma16(s16x8 a, s16x8 b, f32x4 c){
  return __builtin_amdgcn_mfma_f32_16x16x32_bf16(a,b,c,0,0,0);
}
__device__ __forceinline__ f32x16 mfma32(s16x8 a, s16x8 b, f32x16 c){
  return __builtin_amdgcn_mfma_f32_32x32x16_bf16(a,b,c,0,0,0);
}

// ---------------------------------------------------------------------------
// dtype probe (validated rounds 2-11)
// ---------------------------------------------------------------------------
__global__ __launch_bounds__(256) void detect_dtype(const u16* __restrict__ x, u32* __restrict__ flag){
  __shared__ int cnt;
  if (threadIdx.x==0) cnt = 0;
  __syncthreads();
  int local = 0;
  for (int i = threadIdx.x; i < 4096; i += 256){
    u16 v = x[2*i];
    int e = (v>>7)&0xFF;
    if (e >= 140 || e <= 100) local++;
  }
  atomicAdd(&cnt, local);
  __syncthreads();
  if (threadIdx.x==0) *flag = (cnt > 1024) ? 1u : 0u;
}

struct CvtArgs { const void* src[10]; u16* dst[10]; int n[10]; };

// ---------------------------------------------------------------------------
// Merged weight/bias convert (y<10) + x convert-transpose (y==10).
// Grid (2048, 11), block 256.
// ---------------------------------------------------------------------------
__global__ __launch_bounds__(256) void convert_all(
    CvtArgs a, const void* __restrict__ xsrc,
    const u32* __restrict__ flag, u16* __restrict__ xT)
{
  __shared__ u16 T[64][72];
  const int t = threadIdx.x;
  if (blockIdx.y < 10){
    const int which = blockIdx.y;
    const int n = a.n[which];
    const int base = blockIdx.x*2048 + t;
    if (base >= n) return;
    u16* dst = a.dst[which];
    if (*flag){
      const float* s = (const float*)a.src[which];
      #pragma unroll
      for (int j=0;j<8;j++){ int i = base + j*256; if (i<n) dst[i] = f2bf(s[i]); }
    } else {
      const u16* s = (const u16*)a.src[which];
      #pragma unroll
      for (int j=0;j<8;j++){ int i = base + j*256; if (i<n) dst[i] = s[i]; }
    }
    return;
  }
  // ---- x transpose: xT[b][c][s] = cvt(x[b][s][c]) ----
  const int bx = blockIdx.x;
  if (bx >= 1024) return;
  const int s0 = (bx&31)*64, c0 = ((bx>>5)&15)*64, b = bx>>9;
  const int r = t>>2, cc = (t&3)*16;
  const long off = ((long)(b*2048 + s0 + r))*1024 + c0 + cc;
  if (*flag){
    const float* p = (const float*)xsrc + off;
    #pragma unroll
    for (int j=0;j<16;j++) T[r][cc+j] = f2bf(p[j]);
  } else {
    const u16* p = (const u16*)xsrc + off;
    *(s16x8*)&T[r][cc]   = *(const s16x8*)p;
    *(s16x8*)&T[r][cc+8] = *(const s16x8*)(p+8);
  }
  __syncthreads();
  {
    const int orow = t&63, oc = (t>>6)*16;
    u16 tmp[16];
    #pragma unroll
    for (int j=0;j<16;j++) tmp[j] = T[oc+j][orow];
    u16* q = xT + (long)b*2097152 + (long)(c0+orow)*2048 + s0 + oc;
    *(s16x8*)q     = *(s16x8*)&tmp[0];
    *(s16x8*)(q+8) = *(s16x8*)&tmp[8];
  }
}

// ---------------------------------------------------------------------------
// sv[row] = sum_k Mt[row][k]  (softmax rows sum to 1 => equals sum_t v[b,t,c]).
// Grid 512, block 256 (4 waves, 1 Mt-row each).
// ---------------------------------------------------------------------------
__global__ __launch_bounds__(256) void rowsum_mt(const u16* __restrict__ Mt, float* __restrict__ sv){
  const int row = blockIdx.x*4 + (threadIdx.x>>6);
  const int lane = threadIdx.x&63;
  const u16* p = Mt + (long)row*2048;
  float s = 0.f;
  #pragma unroll
  for (int i=0;i<4;i++){
    s16x8 v = *(const s16x8*)&p[i*512 + lane*8];
    #pragma unroll
    for (int j=0;j<8;j++) s += bf2f((u16)v[j]);
  }
  #pragma unroll
  for (int off=32; off>=1; off>>=1) s += __shfl_xor(s, off);
  if (lane==0) sv[row] = s;
}

// ---------------------------------------------------------------------------
// NT GEMM, BM=128 x BN tile, BK=32, double-buffered LDS + global_load_lds(16B).
// (round-5/7 version — proven)
// ---------------------------------------------------------------------------
template<int BN, int BMODE, bool DYN, bool QS>
__global__ __launch_bounds__(256) void gemm_t(
    const u16* __restrict__ A, const u16* __restrict__ B,
    const u16* __restrict__ bias, const float* __restrict__ r1col,
    const u32* __restrict__ dflag, void* __restrict__ C,
    int K, int lda, int ldb, int ldc,
    long aBatch, long bBatch, long cBatch)
{
  constexpr int BM = 128;
  constexpr int ACH = BM/64, BCH = BN/64;
  constexpr int MI = (BN==128) ? 4 : 2;
  __shared__ u16 As[2][BM*32];
  __shared__ u16 Bs[2][BN*32];
  const int t = threadIdx.x, w = t>>6, quad = (t&63)>>4, l16 = t&15;
  const int z = blockIdx.z;
  const int m0 = blockIdx.x*BM, n0 = blockIdx.y*BN;
  const u16* Ag = A + (long)z*aBatch + (long)m0*lda;
  const u16* Bg = B + (long)z*bBatch + (long)n0*ldb;
  const int wm = (BN==128) ? (w>>1)*64 : w*32;
  const int wn = (BN==128) ? (w&1)*64 : 0;

  auto stage = [&](int buf, int k0){
    #pragma unroll
    for (int i=0;i<ACH;i++){
      const int chunk = i*256 + t;
      glds16(Ag + (long)(chunk>>2)*lda + k0 + (chunk&3)*8, &As[buf][(i*256 + w*64)*8]);
    }
    #pragma unroll
    for (int i=0;i<BCH;i++){
      const int chunk = i*256 + t;
      glds16(Bg + (long)(chunk>>2)*ldb + k0 + (chunk&3)*8, &Bs[buf][(i*256 + w*64)*8]);
    }
  };

  f32x4 acc[MI][4];
  #pragma unroll
  for (int i=0;i<MI;i++)
    #pragma unroll
    for (int j=0;j<4;j++) acc[i][j] = (f32x4){0.f,0.f,0.f,0.f};

  stage(0, 0);
  const int nk = K>>5;
  for (int kt=0; kt<nk; ++kt){
    __syncthreads();
    if (kt+1 < nk) stage((kt+1)&1, (kt+1)<<5);
    const u16* as = As[kt&1];
    const u16* bs = Bs[kt&1];
    s16x8 a[MI], bb[4];
    #pragma unroll
    for (int i=0;i<MI;i++) a[i] = *(const s16x8*)&as[(wm + i*16 + l16)*32 + quad*8];
    #pragma unroll
    for (int j=0;j<4;j++)  bb[j]= *(const s16x8*)&bs[(wn + j*16 + l16)*32 + quad*8];
    #pragma unroll
    for (int i=0;i<MI;i++)
      #pragma unroll
      for (int j=0;j<4;j++)
        acc[i][j] = mfma16(a[i], bb[j], acc[i][j]);
  }

  bool f32o = false;
  if (DYN) f32o = (*dflag != 0);
  #pragma unroll
  for (int i=0;i<MI;i++){
    #pragma unroll
    for (int j=0;j<4;j++){
      const int col = n0 + wn + j*16 + l16;
      #pragma unroll
      for (int r=0;r<4;r++){
        const int row = m0 + wm + i*16 + quad*4 + r;
        float vv = acc[i][j][r];
        if (BMODE==1) vv += bf2f(bias[row]);
        if (BMODE==2) vv += bf2f(bias[col]);
        if (BMODE==3) vv += bf2f(bias[row]) * r1col[z*1024 + col];
        if (QS){ if (col < 1024) vv *= SCL; }
        const long idx = (long)z*cBatch + (long)row*ldc + col;
        if (DYN && f32o) ((float*)C)[idx] = vv;
        else             ((u16*)C)[idx]   = f2bf(vv);
      }
    }
  }
}

// ---------------------------------------------------------------------------
// Fused softmax-denominator + V-scale-transpose.
// R16: K-loop double-buffered -> ONE barrier per iteration; reg->LDS write of
// tile kc+1 overlaps with tile kc's MFMA/exp compute.  LDS 26.9 KB.
// ---------------------------------------------------------------------------
__global__ __launch_bounds__(256) void attn_stats(const u16* __restrict__ qkv, u16* __restrict__ VtG){
  __shared__ u16 Qs[64][68];
  __shared__ u16 Ks[2][64][68];
  __shared__ float red[2][64];
  __shared__ float ilv[64];
  const int q0 = blockIdx.x*64, bh = blockIdx.y, b = bh>>4, h = bh&15;
  const int t = threadIdx.x, w = t>>6, l32 = t&31, half = (t&63)>>5;
  const int wq = w>>1, wk = w&1;
  const int r = t>>2, cc = (t&3)*16;
  {
    const u16* p = &qkv[((long)(b*2048 + q0 + r))*3072 + h*64 + cc];
    *(s16x8*)&Qs[r][cc]   = *(const s16x8*)p;
    *(s16x8*)&Qs[r][cc+8] = *(const s16x8*)(p+8);
  }
  const u16* kg = &qkv[((long)(b*2048 + r))*3072 + 1024 + h*64 + cc];
  // tile0 -> regs -> Ks[0]; prefetch tile1 into regs
  s16x8 sk0 = *(const s16x8*)kg;
  s16x8 sk1 = *(const s16x8*)(kg+8);
  *(s16x8*)&Ks[0][r][cc]   = sk0;
  *(s16x8*)&Ks[0][r][cc+8] = sk1;
  sk0 = *(const s16x8*)(kg + (long)64*3072);
  sk1 = *(const s16x8*)(kg + (long)64*3072 + 8);
  __syncthreads();                     // Qs + Ks[0] visible
  s16x8 aq[4];
  #pragma unroll
  for (int u=0;u<4;u++) aq[u] = *(s16x8*)&Qs[wq*32 + l32][u*16 + half*8];
  float lp[16];
  #pragma unroll
  for (int r2=0;r2<16;r2++) lp[r2] = 0.f;

  for (int kc=0; kc<32; ++kc){
    __syncthreads();                   // Ks[cur] writes visible; prev reads of Ks[cur^1] done
    const int cur = kc&1;
    if (kc+1 < 32){
      *(s16x8*)&Ks[cur^1][r][cc]   = sk0;
      *(s16x8*)&Ks[cur^1][r][cc+8] = sk1;
      if (kc+2 < 32){
        sk0 = *(const s16x8*)(kg + (long)(kc+2)*64*3072);
        sk1 = *(const s16x8*)(kg + (long)(kc+2)*64*3072 + 8);
      }
    }
    s16x8 kb[4];
    #pragma unroll
    for (int u=0;u<4;u++) kb[u] = *(s16x8*)&Ks[cur][wk*32 + l32][u*16 + half*8];
    f32x16 acc = {};
    #pragma unroll
    for (int u=0;u<4;u++) acc = mfma32(aq[u], kb[u], acc);
    #pragma unroll
    for (int r2=0;r2<16;r2++) lp[r2] += EXP2(acc[r2]);
  }
  #pragma unroll
  for (int off=1; off<32; off<<=1)
    #pragma unroll
    for (int r2=0;r2<16;r2++) lp[r2] += __shfl_xor(lp[r2], off);
  if (l32 == 0){
    #pragma unroll
    for (int r2=0;r2<16;r2++)
      red[wk][wq*32 + 4*half + (r2&3) + 8*(r2>>2)] = lp[r2];
  }
  __syncthreads();
  if (t < 64) ilv[t] = 1.f / (red[0][t] + red[1][t]);
  __syncthreads();
  // ---- fused V scale+transpose through Qs (dead after aq) ----
  {
    const u16* p = &qkv[((long)(b*2048 + q0 + r))*3072 + 2048 + h*64 + cc];
    const float sc = ilv[r];
    s16x8 v0 = *(const s16x8*)p, v1 = *(const s16x8*)(p+8);
    #pragma unroll
    for (int j=0;j<8;j++){
      Qs[r][cc+j]   = f2bf(bf2f((u16)v0[j])*sc);
      Qs[r][cc+8+j] = f2bf(bf2f((u16)v1[j])*sc);
    }
  }
  __syncthreads();
  {
    const int orow = t&63, oc = (t>>6)*16;
    u16 tmp[16];
    #pragma unroll
    for (int j=0;j<16;j++) tmp[j] = Qs[oc+j][orow];
    u16* q = VtG + (long)b*2097152 + (long)(h*64+orow)*2048 + q0 + oc;
    *(s16x8*)q     = *(s16x8*)&tmp[0];
    *(s16x8*)(q+8) = *(s16x8*)&tmp[8];
  }
}

// ---------------------------------------------------------------------------
// Mt[b, h*64+d, k] = sum_q exp2(q'.k) * vtilde[d,q]   (V pre-scaled by il[q]).
// R16: R14 structure (proven 51.8 us) + double-buffered Qs/Vs -> ONE barrier
// per iteration; reg->LDS writes of tile i+1 overlap tile i's compute.
// cvt_pk_bf16_f32 pack (verified in R15).  Wave-private P via
// v_permlane32_swap_b32 (R13-verified).  Grid (16,32), block 256, LDS 34.8 KB.
// ---------------------------------------------------------------------------
__global__ __launch_bounds__(256,2) void attn_pv(
    const u16* __restrict__ qkv, const u16* __restrict__ VtG, u16* __restrict__ Mt)
{
  __shared__ u16 Qs[2][64][68];
  __shared__ u16 Vs[2][64][68];
  const int t = threadIdx.x, w = t>>6, l32 = t&31, hi = (t&63)>>5;
  const int bh = blockIdx.y, b = bh>>4, h = bh&15;
  const int kcol = blockIdx.x*128 + w*32 + l32;
  const int r = t>>2, cc = (t&3)*16;

  // K fragments (B-op of QK): lane holds K[kcol][d = c*16 + hi*8 + j].
  // One-time uncoalesced global load (L2-cached), persistent in regs.
  const u16* kp = qkv + ((long)(b*2048 + kcol))*3072 + 1024 + h*64 + hi*8;
  s16x8 kb[4];
  #pragma unroll
  for (int c=0;c<4;c++) kb[c] = *(const s16x8*)(kp + c*16);

  // coalesced staging pointers: thread loads row r, cols cc..cc+15
  const u16* qg = &qkv[((long)(b*2048 + r))*3072 + h*64 + cc];
  const u16* vg = &VtG[((long)(b*1024 + h*64 + r))*2048 + cc];

  // tile0 -> regs -> buf0; prefetch tile1 into regs
  s16x8 sq0 = *(const s16x8*)qg, sq1 = *(const s16x8*)(qg+8);
  s16x8 sv0 = *(const s16x8*)vg, sv1 = *(const s16x8*)(vg+8);
  *(s16x8*)&Qs[0][r][cc]   = sq0;  *(s16x8*)&Qs[0][r][cc+8] = sq1;
  *(s16x8*)&Vs[0][r][cc]   = sv0;  *(s16x8*)&Vs[0][r][cc+8] = sv1;
  {
    const u16* nq = qg + (long)64*3072;
    const u16* nv = vg + 64;
    sq0 = *(const s16x8*)nq; sq1 = *(const s16x8*)(nq+8);
    sv0 = *(const s16x8*)nv; sv1 = *(const s16x8*)(nv+8);
  }

  f32x16 accM0 = {}, accM1 = {};
  for (int i=0; i<32; ++i){
    __syncthreads();                 // buf[cur] writes visible; prev reads of buf[cur^1] done
    const int cur = i&1;
    if (i+1 < 32){                   // write tile i+1 (overlaps with compute below)
      *(s16x8*)&Qs[cur^1][r][cc]   = sq0;  *(s16x8*)&Qs[cur^1][r][cc+8] = sq1;
      *(s16x8*)&Vs[cur^1][r][cc]   = sv0;  *(s16x8*)&Vs[cur^1][r][cc+8] = sv1;
      if (i+2 < 32){                 // T14: issue tile i+2 loads (2-iteration cover)
        const u16* nq = qg + (long)(i+2)*64*3072;
        const u16* nv = vg + (i+2)*64;
        sq0 = *(const s16x8*)nq; sq1 = *(const s16x8*)(nq+8);
        sv0 = *(const s16x8*)nv; sv1 = *(const s16x8*)(nv+8);
      }
    }
    // fragments from buf[cur] (per wave: full 64-q range, own 32 kcols)
    s16x8 aq0[4], aq1[4];
    #pragma unroll
    for (int c=0;c<4;c++){
      aq0[c] = *(s16x8*)&Qs[cur][l32][c*16 + hi*8];
      aq1[c] = *(s16x8*)&Qs[cur][32+l32][c*16 + hi*8];
    }
    f32x16 acc0 = {}, acc1 = {};
    #pragma unroll
    for (int c=0;c<4;c++){
      acc0 = mfma32(aq0[c], kb[c], acc0);
      acc1 = mfma32(aq1[c], kb[c], acc1);
    }
    // exp -> cvt_pk_bf16 -> permlane32_swap: PV B-fragments in-register
    // (R13-verified layout). C/D: lane holds P[q = qt*32 + (r&3)+8*(r>>2)+4*hi][kcol];
    // B-frag bp[c] needs P[q = c*16 + 8*hi + j][kcol].
    s16x8 bp[4];
    #pragma unroll
    for (int qt=0;qt<2;qt++){
      float p[16];
      #pragma unroll
      for (int r2=0;r2<16;r2++) p[r2] = EXP2(qt ? acc1[r2] : acc0[r2]);
      #pragma unroll
      for (int ccc=0; ccc<2; ccc++){
        u32 X0, X1, Y0, Y1;
        asm("v_cvt_pk_bf16_f32 %0, %1, %2" : "=v"(X0) : "v"(p[ccc*8+0]), "v"(p[ccc*8+1]));
        asm("v_cvt_pk_bf16_f32 %0, %1, %2" : "=v"(X1) : "v"(p[ccc*8+2]), "v"(p[ccc*8+3]));
        asm("v_cvt_pk_bf16_f32 %0, %1, %2" : "=v"(Y0) : "v"(p[ccc*8+4]), "v"(p[ccc*8+5]));
        asm("v_cvt_pk_bf16_f32 %0, %1, %2" : "=v"(Y1) : "v"(p[ccc*8+6]), "v"(p[ccc*8+7]));
        asm volatile("v_permlane32_swap_b32 %0, %1" : "+v"(X0), "+v"(Y0));
        asm volatile("v_permlane32_swap_b32 %0, %1" : "+v"(X1), "+v"(Y1));
        u32x4 dw; dw[0]=X0; dw[1]=X1; dw[2]=Y0; dw[3]=Y1;
        bp[qt*2+ccc] = __builtin_bit_cast(s16x8, dw);
      }
    }
    // PV: accM[i] covers d = i*32..+32 x k = kcol, contraction over this q-tile
    s16x8 av0[4], av1[4];
    #pragma unroll
    for (int c=0;c<4;c++){
      av0[c] = *(s16x8*)&Vs[cur][l32][c*16 + hi*8];
      av1[c] = *(s16x8*)&Vs[cur][32+l32][c*16 + hi*8];
    }
    #pragma unroll
    for (int c=0;c<4;c++){
      accM0 = mfma32(av0[c], bp[c], accM0);
      accM1 = mfma32(av1[c], bp[c], accM1);
    }
  }
  #pragma unroll
  for (int r2=0;r2<16;r2++){
    const int d0 = 4*hi + (r2&3) + 8*(r2>>2);
    Mt[((long)(b*1024 + h*64 + d0))*2048 + kcol]      = f2bf(accM0[r2]);
    Mt[((long)(b*1024 + h*64 + d0 + 32))*2048 + kcol] = f2bf(accM1[r2]);
  }
}

extern "C" void kernel_launch(void* const* d_in, const int* in_sizes, int n_in,
                              void* d_out, int out_size, void* d_ws, size_t ws_size,
                              hipStream_t stream)
{
  (void)n_in; (void)out_size; (void)ws_size;
  char* ws = (char*)d_ws;
  u32*  dflag = (u32*)ws;            ws += 64;
  u16*  whc   = (u16*)ws;            ws += (size_t)8388608;
  u16*  wqkvc = (u16*)ws;            ws += (size_t)6291456;
  u16*  woc   = (u16*)ws;            ws += (size_t)8388608;
  u16*  bhc   = (u16*)ws;            ws += 4096;
  u16*  bqkvc = (u16*)ws;            ws += 8192;
  u16*  boc   = (u16*)ws;            ws += 4096;
  u16*  xT    = (u16*)ws;            ws += (size_t)8388608;
  u16*  xh    = (u16*)ws;            ws += (size_t)8388608;
  u16*  qkvb  = (u16*)ws;            ws += (size_t)25165824;
  u16*  VtG   = (u16*)ws;            ws += (size_t)8388608;
  u16*  Mt    = (u16*)ws;            ws += (size_t)8388608;
  float* sv   = (float*)ws;          ws += 8192;

  // 0) probe dtype + canonicalize all inputs (weights/biases + x-transpose fused)
  detect_dtype<<<1,256,0,stream>>>((const u16*)d_in[0], dflag);
  CvtArgs ca;
  const void* srcs[10] = {d_in[1], d_in[2], d_in[3], d_in[4], d_in[5],
                          d_in[6], d_in[7], d_in[8], d_in[9], d_in[10]};
  u16* dsts[10] = {whc, bhc, wqkvc, bqkvc, wqkvc+1048576, bqkvc+1024,
                   wqkvc+2097152, bqkvc+2048, woc, boc};
  const int ns[10] = {in_sizes[1], in_sizes[2], in_sizes[3], in_sizes[4], in_sizes[5],
                      in_sizes[6], in_sizes[7], in_sizes[8], in_sizes[9], in_sizes[10]};
  for (int i=0;i<10;i++){ ca.src[i]=srcs[i]; ca.dst[i]=dsts[i]; ca.n[i]=ns[i]; }
  convert_all<<<dim3(2048,11),256,0,stream>>>(ca, d_in[0], dflag, xT);

  const long S2M = 2097152L;   // 2048*1024

  // 1) xh = w_hseq @ xT^T + b_hseq   (NT, row bias)
  gemm_t<64,1,false,false><<<dim3(16,16,2),256,0,stream>>>(whc, xT, bhc, nullptr, dflag, xh,
      2048, 2048, 2048, 1024, 0L, S2M, S2M);

  // 2) qkv = xh @ Wqkv^T + bqkv; q-columns pre-scaled by SCL   (NT, col bias)
  gemm_t<128,2,false,true><<<dim3(16,24,2),256,0,stream>>>(xh, wqkvc, bqkvc, nullptr, dflag, qkvb,
      1024, 1024, 1024, 3072, S2M, 0L, (long)2048*3072);

  // 3) softmax denominators + fused V scale-transpose -> VtG  (R16 dbuf)
  attn_stats<<<dim3(32,32),256,0,stream>>>(qkvb, VtG);

  // 4) Mt = (attn^T @ v)^T   (R16: dbuf single-barrier + in-register P)
  attn_pv<<<dim3(16,32),256,0,stream>>>(qkvb, VtG, Mt);

  // 5) sv[b,c] = sum_k Mt[b,c,k]  (softmax rows sum to 1 => = sum_t v[b,t,c])
  rowsum_mt<<<512,256,0,stream>>>(Mt, sv);

  // 6) out = w_oseq @ Mt^T + b_oseq (x) sv   (NT, rank-1 bias, dyn dtype)
  gemm_t<64,3,true,false><<<dim3(16,16,2),256,0,stream>>>(woc, Mt, boc, sv, dflag, d_out,
      2048, 2048, 2048, 1024, 0L, S2M, S2M);
}

// Round 6
// 308.946 us; speedup vs baseline: 1.0363x; 1.0047x over previous
//
#include <hip/hip_runtime.h>
#include <hip/hip_bf16.h>

typedef unsigned short u16;
typedef unsigned int u32;
typedef unsigned long long u64;
typedef __attribute__((ext_vector_type(8))) short s16x8;
typedef __attribute__((ext_vector_type(4))) u32 u32x4;
typedef __attribute__((ext_vector_type(4))) float f32x4;
typedef __attribute__((ext_vector_type(16))) float f32x16;

#define SCL 0.1803368867f   // 0.125 * log2(e): exp(s/8) = 2^(s*SCL)

#if __has_builtin(__builtin_amdgcn_exp2f)
#define EXP2(x) __builtin_amdgcn_exp2f(x)
#else
#define EXP2(x) exp2f(x)
#endif

__device__ __forceinline__ float bf2f(u16 v){ u32 u = ((u32)v)<<16; return __builtin_bit_cast(float,u); }
__device__ __forceinline__ u16 f2bf(float f){
  u32 u = __builtin_bit_cast(u32,f);
  u += 0x7fff + ((u>>16)&1);
  return (u16)(u>>16);
}
__device__ __forceinline__ u32 pkbf(float a, float b){   // pack 2 bf16
  u32 ua = __builtin_bit_cast(u32,a) + 0x8000u;
  u32 ub = __builtin_bit_cast(u32,b) + 0x8000u;
  return (ua>>16) | (ub & 0xFFFF0000u);
}
// async global->LDS, 16B per lane; lds_u MUST be wave-uniform (HW adds lane*16)
__device__ __forceinline__ void glds16(const u16* g, const u16* lds_u){
  __builtin_amdgcn_global_load_lds(
      (const __attribute__((address_space(1))) void*)(u64)g,
      (__attribute__((address_space(3))) void*)(u32)(u64)lds_u,
      16, 0, 0);
}
__device__ __forceinline__ f32x4 mfma16(s16x8 a, s16x8 b, f32x4 c){
  return __builtin_amdgcn_mfma_f32_16x16x32_bf16(a,b,c,0,0,0);
}
__device__ __forceinline__ f32x16 mfma32(s16x8 a, s16x8 b, f32x16 c){
  return __builtin_amdgcn_mfma_f32_32x32x16_bf16(a,b,c,0,0,0);
}

// ---------------------------------------------------------------------------
// dtype probe (validated rounds 2-11)
// ---------------------------------------------------------------------------
__global__ __launch_bounds__(256) void detect_dtype(const u16* __restrict__ x, u32* __restrict__ flag){
  __shared__ int cnt;
  if (threadIdx.x==0) cnt = 0;
  __syncthreads();
  int local = 0;
  for (int i = threadIdx.x; i < 4096; i += 256){
    u16 v = x[2*i];
    int e = (v>>7)&0xFF;
    if (e >= 140 || e <= 100) local++;
  }
  atomicAdd(&cnt, local);
  __syncthreads();
  if (threadIdx.x==0) *flag = (cnt > 1024) ? 1u : 0u;
}

struct CvtArgs { const void* src[10]; u16* dst[10]; int n[10]; };

// ---------------------------------------------------------------------------
// Merged weight/bias convert (y<10) + x convert-transpose (y==10).
// Grid (2048, 11), block 256.
// ---------------------------------------------------------------------------
__global__ __launch_bounds__(256) void convert_all(
    CvtArgs a, const void* __restrict__ xsrc,
    const u32* __restrict__ flag, u16* __restrict__ xT)
{
  __shared__ u16 T[64][72];
  const int t = threadIdx.x;
  if (blockIdx.y < 10){
    const int which = blockIdx.y;
    const int n = a.n[which];
    const int base = blockIdx.x*2048 + t;
    if (base >= n) return;
    u16* dst = a.dst[which];
    if (*flag){
      const float* s = (const float*)a.src[which];
      #pragma unroll
      for (int j=0;j<8;j++){ int i = base + j*256; if (i<n) dst[i] = f2bf(s[i]); }
    } else {
      const u16* s = (const u16*)a.src[which];
      #pragma unroll
      for (int j=0;j<8;j++){ int i = base + j*256; if (i<n) dst[i] = s[i]; }
    }
    return;
  }
  // ---- x transpose: xT[b][c][s] = cvt(x[b][s][c]) ----
  const int bx = blockIdx.x;
  if (bx >= 1024) return;
  const int s0 = (bx&31)*64, c0 = ((bx>>5)&15)*64, b = bx>>9;
  const int r = t>>2, cc = (t&3)*16;
  const long off = ((long)(b*2048 + s0 + r))*1024 + c0 + cc;
  if (*flag){
    const float* p = (const float*)xsrc + off;
    #pragma unroll
    for (int j=0;j<16;j++) T[r][cc+j] = f2bf(p[j]);
  } else {
    const u16* p = (const u16*)xsrc + off;
    *(s16x8*)&T[r][cc]   = *(const s16x8*)p;
    *(s16x8*)&T[r][cc+8] = *(const s16x8*)(p+8);
  }
  __syncthreads();
  {
    const int orow = t&63, oc = (t>>6)*16;
    u16 tmp[16];
    #pragma unroll
    for (int j=0;j<16;j++) tmp[j] = T[oc+j][orow];
    u16* q = xT + (long)b*2097152 + (long)(c0+orow)*2048 + s0 + oc;
    *(s16x8*)q     = *(s16x8*)&tmp[0];
    *(s16x8*)(q+8) = *(s16x8*)&tmp[8];
  }
}

// ---------------------------------------------------------------------------
// sv[row] = sum_k Mt[row][k]  (softmax rows sum to 1 => equals sum_t v[b,t,c]).
// Grid 512, block 256 (4 waves, 1 Mt-row each).
// ---------------------------------------------------------------------------
__global__ __launch_bounds__(256) void rowsum_mt(const u16* __restrict__ Mt, float* __restrict__ sv){
  const int row = blockIdx.x*4 + (threadIdx.x>>6);
  const int lane = threadIdx.x&63;
  const u16* p = Mt + (long)row*2048;
  float s = 0.f;
  #pragma unroll
  for (int i=0;i<4;i++){
    s16x8 v = *(const s16x8*)&p[i*512 + lane*8];
    #pragma unroll
    for (int j=0;j<8;j++) s += bf2f((u16)v[j]);
  }
  #pragma unroll
  for (int off=32; off>=1; off>>=1) s += __shfl_xor(s, off);
  if (lane==0) sv[row] = s;
}

// ---------------------------------------------------------------------------
// NT GEMM, BM=128 x BN tile, BK=32, double-buffered LDS + global_load_lds(16B).
// (round-5/7 version — proven)
// ---------------------------------------------------------------------------
template<int BN, int BMODE, bool DYN, bool QS>
__global__ __launch_bounds__(256) void gemm_t(
    const u16* __restrict__ A, const u16* __restrict__ B,
    const u16* __restrict__ bias, const float* __restrict__ r1col,
    const u32* __restrict__ dflag, void* __restrict__ C,
    int K, int lda, int ldb, int ldc,
    long aBatch, long bBatch, long cBatch)
{
  constexpr int BM = 128;
  constexpr int ACH = BM/64, BCH = BN/64;
  constexpr int MI = (BN==128) ? 4 : 2;
  __shared__ u16 As[2][BM*32];
  __shared__ u16 Bs[2][BN*32];
  const int t = threadIdx.x, w = t>>6, quad = (t&63)>>4, l16 = t&15;
  const int z = blockIdx.z;
  const int m0 = blockIdx.x*BM, n0 = blockIdx.y*BN;
  const u16* Ag = A + (long)z*aBatch + (long)m0*lda;
  const u16* Bg = B + (long)z*bBatch + (long)n0*ldb;
  const int wm = (BN==128) ? (w>>1)*64 : w*32;
  const int wn = (BN==128) ? (w&1)*64 : 0;

  auto stage = [&](int buf, int k0){
    #pragma unroll
    for (int i=0;i<ACH;i++){
      const int chunk = i*256 + t;
      glds16(Ag + (long)(chunk>>2)*lda + k0 + (chunk&3)*8, &As[buf][(i*256 + w*64)*8]);
    }
    #pragma unroll
    for (int i=0;i<BCH;i++){
      const int chunk = i*256 + t;
      glds16(Bg + (long)(chunk>>2)*ldb + k0 + (chunk&3)*8, &Bs[buf][(i*256 + w*64)*8]);
    }
  };

  f32x4 acc[MI][4];
  #pragma unroll
  for (int i=0;i<MI;i++)
    #pragma unroll
    for (int j=0;j<4;j++) acc[i][j] = (f32x4){0.f,0.f,0.f,0.f};

  stage(0, 0);
  const int nk = K>>5;
  for (int kt=0; kt<nk; ++kt){
    __syncthreads();
    if (kt+1 < nk) stage((kt+1)&1, (kt+1)<<5);
    const u16* as = As[kt&1];
    const u16* bs = Bs[kt&1];
    s16x8 a[MI], bb[4];
    #pragma unroll
    for (int i=0;i<MI;i++) a[i] = *(const s16x8*)&as[(wm + i*16 + l16)*32 + quad*8];
    #pragma unroll
    for (int j=0;j<4;j++)  bb[j]= *(const s16x8*)&bs[(wn + j*16 + l16)*32 + quad*8];
    #pragma unroll
    for (int i=0;i<MI;i++)
      #pragma unroll
      for (int j=0;j<4;j++)
        acc[i][j] = mfma16(a[i], bb[j], acc[i][j]);
  }

  bool f32o = false;
  if (DYN) f32o = (*dflag != 0);
  #pragma unroll
  for (int i=0;i<MI;i++){
    #pragma unroll
    for (int j=0;j<4;j++){
      const int col = n0 + wn + j*16 + l16;
      #pragma unroll
      for (int r=0;r<4;r++){
        const int row = m0 + wm + i*16 + quad*4 + r;
        float vv = acc[i][j][r];
        if (BMODE==1) vv += bf2f(bias[row]);
        if (BMODE==2) vv += bf2f(bias[col]);
        if (BMODE==3) vv += bf2f(bias[row]) * r1col[z*1024 + col];
        if (QS){ if (col < 1024) vv *= SCL; }
        const long idx = (long)z*cBatch + (long)row*ldc + col;
        if (DYN && f32o) ((float*)C)[idx] = vv;
        else             ((u16*)C)[idx]   = f2bf(vv);
      }
    }
  }
}

// ---------------------------------------------------------------------------
// Fused softmax-denominator + V-scale-transpose (R16 dbuf version — proven).
// ---------------------------------------------------------------------------
__global__ __launch_bounds__(256) void attn_stats(const u16* __restrict__ qkv, u16* __restrict__ VtG){
  __shared__ u16 Qs[64][68];
  __shared__ u16 Ks[2][64][68];
  __shared__ float red[2][64];
  __shared__ float ilv[64];
  const int q0 = blockIdx.x*64, bh = blockIdx.y, b = bh>>4, h = bh&15;
  const int t = threadIdx.x, w = t>>6, l32 = t&31, half = (t&63)>>5;
  const int wq = w>>1, wk = w&1;
  const int r = t>>2, cc = (t&3)*16;
  {
    const u16* p = &qkv[((long)(b*2048 + q0 + r))*3072 + h*64 + cc];
    *(s16x8*)&Qs[r][cc]   = *(const s16x8*)p;
    *(s16x8*)&Qs[r][cc+8] = *(const s16x8*)(p+8);
  }
  const u16* kg = &qkv[((long)(b*2048 + r))*3072 + 1024 + h*64 + cc];
  // tile0 -> regs -> Ks[0]; prefetch tile1 into regs
  s16x8 sk0 = *(const s16x8*)kg;
  s16x8 sk1 = *(const s16x8*)(kg+8);
  *(s16x8*)&Ks[0][r][cc]   = sk0;
  *(s16x8*)&Ks[0][r][cc+8] = sk1;
  sk0 = *(const s16x8*)(kg + (long)64*3072);
  sk1 = *(const s16x8*)(kg + (long)64*3072 + 8);
  __syncthreads();                     // Qs + Ks[0] visible
  s16x8 aq[4];
  #pragma unroll
  for (int u=0;u<4;u++) aq[u] = *(s16x8*)&Qs[wq*32 + l32][u*16 + half*8];
  float lp[16];
  #pragma unroll
  for (int r2=0;r2<16;r2++) lp[r2] = 0.f;

  for (int kc=0; kc<32; ++kc){
    __syncthreads();                   // Ks[cur] writes visible; prev reads of Ks[cur^1] done
    const int cur = kc&1;
    if (kc+1 < 32){
      *(s16x8*)&Ks[cur^1][r][cc]   = sk0;
      *(s16x8*)&Ks[cur^1][r][cc+8] = sk1;
      if (kc+2 < 32){
        sk0 = *(const s16x8*)(kg + (long)(kc+2)*64*3072);
        sk1 = *(const s16x8*)(kg + (long)(kc+2)*64*3072 + 8);
      }
    }
    s16x8 kb[4];
    #pragma unroll
    for (int u=0;u<4;u++) kb[u] = *(s16x8*)&Ks[cur][wk*32 + l32][u*16 + half*8];
    f32x16 acc = {};
    #pragma unroll
    for (int u=0;u<4;u++) acc = mfma32(aq[u], kb[u], acc);
    #pragma unroll
    for (int r2=0;r2<16;r2++) lp[r2] += EXP2(acc[r2]);
  }
  #pragma unroll
  for (int off=1; off<32; off<<=1)
    #pragma unroll
    for (int r2=0;r2<16;r2++) lp[r2] += __shfl_xor(lp[r2], off);
  if (l32 == 0){
    #pragma unroll
    for (int r2=0;r2<16;r2++)
      red[wk][wq*32 + 4*half + (r2&3) + 8*(r2>>2)] = lp[r2];
  }
  __syncthreads();
  if (t < 64) ilv[t] = 1.f / (red[0][t] + red[1][t]);
  __syncthreads();
  // ---- fused V scale+transpose through Qs (dead after aq) ----
  {
    const u16* p = &qkv[((long)(b*2048 + q0 + r))*3072 + 2048 + h*64 + cc];
    const float sc = ilv[r];
    s16x8 v0 = *(const s16x8*)p, v1 = *(const s16x8*)(p+8);
    #pragma unroll
    for (int j=0;j<8;j++){
      Qs[r][cc+j]   = f2bf(bf2f((u16)v0[j])*sc);
      Qs[r][cc+8+j] = f2bf(bf2f((u16)v1[j])*sc);
    }
  }
  __syncthreads();
  {
    const int orow = t&63, oc = (t>>6)*16;
    u16 tmp[16];
    #pragma unroll
    for (int j=0;j<16;j++) tmp[j] = Qs[oc+j][orow];
    u16* q = VtG + (long)b*2097152 + (long)(h*64+orow)*2048 + q0 + oc;
    *(s16x8*)q     = *(s16x8*)&tmp[0];
    *(s16x8*)(q+8) = *(s16x8*)&tmp[8];
  }
}

// ---------------------------------------------------------------------------
// Mt[b, h*64+d, k] = sum_q exp2(q'.k) * vtilde[d,q]   (V pre-scaled by il[q]).
// R17: R16 structure + 128-row staging (2 sub-tiles per iteration, 16 iters).
// The two sub-tiles are independent until the accM accumulate, so sub-B's
// QK MFMAs overlap sub-A's exp/pack VALU phase within each wave (T15-style
// in-register pipeline), and one barrier amortizes over 2x compute.
// Wave-private P via permlane32_swap (R13-verified) + cvt_pk pack (R15).
// Grid (16,32), block 256, LDS 69.6 KB -> 2 blocks/CU (139 < 160 KB).
// ---------------------------------------------------------------------------
__global__ __launch_bounds__(256,2) void attn_pv(
    const u16* __restrict__ qkv, const u16* __restrict__ VtG, u16* __restrict__ Mt)
{
  __shared__ u16 Qs[2][2][64][68];   // [dbuf][sub][row][col]
  __shared__ u16 Vs[2][2][64][68];
  const int t = threadIdx.x, w = t>>6, l32 = t&31, hi = (t&63)>>5;
  const int bh = blockIdx.y, b = bh>>4, h = bh&15;
  const int kcol = blockIdx.x*128 + w*32 + l32;
  const int r = t>>2, cc = (t&3)*16;

  // K fragments (B-op of QK): lane holds K[kcol][d = c*16 + hi*8 + j].
  // One-time uncoalesced global load (L2-cached), persistent in regs.
  const u16* kp = qkv + ((long)(b*2048 + kcol))*3072 + 1024 + h*64 + hi*8;
  s16x8 kb[4];
  #pragma unroll
  for (int c=0;c<4;c++) kb[c] = *(const s16x8*)(kp + c*16);

  // coalesced staging pointers: thread loads row r, cols cc..cc+15
  const u16* qg = &qkv[((long)(b*2048 + r))*3072 + h*64 + cc];
  const u16* vg = &VtG[((long)(b*1024 + h*64 + r))*2048 + cc];

  // tile0 (128 rows = 2 subs) -> regs -> buf0; prefetch tile1 into regs
  s16x8 sq[2][2], sv[2][2];          // [sub][half]
  #pragma unroll
  for (int s=0;s<2;s++){
    const u16* nq = qg + (long)(s*64)*3072;
    const u16* nv = vg + s*64;
    sq[s][0] = *(const s16x8*)nq; sq[s][1] = *(const s16x8*)(nq+8);
    sv[s][0] = *(const s16x8*)nv; sv[s][1] = *(const s16x8*)(nv+8);
  }
  #pragma unroll
  for (int s=0;s<2;s++){
    *(s16x8*)&Qs[0][s][r][cc]   = sq[s][0];  *(s16x8*)&Qs[0][s][r][cc+8] = sq[s][1];
    *(s16x8*)&Vs[0][s][r][cc]   = sv[s][0];  *(s16x8*)&Vs[0][s][r][cc+8] = sv[s][1];
  }
  #pragma unroll
  for (int s=0;s<2;s++){
    const u16* nq = qg + (long)(128 + s*64)*3072;
    const u16* nv = vg + 128 + s*64;
    sq[s][0] = *(const s16x8*)nq; sq[s][1] = *(const s16x8*)(nq+8);
    sv[s][0] = *(const s16x8*)nv; sv[s][1] = *(const s16x8*)(nv+8);
  }

  f32x16 accM0 = {}, accM1 = {};
  for (int i=0; i<16; ++i){
    __syncthreads();                 // buf[cur] writes visible; prev reads of buf[cur^1] done
    const int cur = i&1;
    if (i+1 < 16){                   // write tile i+1 (overlaps with compute below)
      #pragma unroll
      for (int s=0;s<2;s++){
        *(s16x8*)&Qs[cur^1][s][r][cc]   = sq[s][0];  *(s16x8*)&Qs[cur^1][s][r][cc+8] = sq[s][1];
        *(s16x8*)&Vs[cur^1][s][r][cc]   = sv[s][0];  *(s16x8*)&Vs[cur^1][s][r][cc+8] = sv[s][1];
      }
      if (i+2 < 16){                 // T14: issue tile i+2 loads (2-iteration cover)
        #pragma unroll
        for (int s=0;s<2;s++){
          const u16* nq = qg + (long)((i+2)*128 + s*64)*3072;
          const u16* nv = vg + (i+2)*128 + s*64;
          sq[s][0] = *(const s16x8*)nq; sq[s][1] = *(const s16x8*)(nq+8);
          sv[s][0] = *(const s16x8*)nv; sv[s][1] = *(const s16x8*)(nv+8);
        }
      }
    }
    // two independent sub-tiles: compiler interleaves sub1's QK MFMAs with
    // sub0's exp/pack VALU (separate pipes), hiding the serial phases.
    #pragma unroll
    for (int s=0;s<2;s++){
      s16x8 aq0[4], aq1[4];
      #pragma unroll
      for (int c=0;c<4;c++){
        aq0[c] = *(s16x8*)&Qs[cur][s][l32][c*16 + hi*8];
        aq1[c] = *(s16x8*)&Qs[cur][s][32+l32][c*16 + hi*8];
      }
      f32x16 acc0 = {}, acc1 = {};
      #pragma unroll
      for (int c=0;c<4;c++){
        acc0 = mfma32(aq0[c], kb[c], acc0);
        acc1 = mfma32(aq1[c], kb[c], acc1);
      }
      // exp -> cvt_pk_bf16 -> permlane32_swap: PV B-fragments in-register
      // (R13-verified layout). C/D: lane holds P[q = qt*32 + (r&3)+8*(r>>2)+4*hi][kcol];
      // B-frag bp[c] needs P[q = c*16 + 8*hi + j][kcol].
      s16x8 bp[4];
      #pragma unroll
      for (int qt=0;qt<2;qt++){
        float p[16];
        #pragma unroll
        for (int r2=0;r2<16;r2++) p[r2] = EXP2(qt ? acc1[r2] : acc0[r2]);
        #pragma unroll
        for (int ccc=0; ccc<2; ccc++){
          u32 X0, X1, Y0, Y1;
          asm("v_cvt_pk_bf16_f32 %0, %1, %2" : "=v"(X0) : "v"(p[ccc*8+0]), "v"(p[ccc*8+1]));
          asm("v_cvt_pk_bf16_f32 %0, %1, %2" : "=v"(X1) : "v"(p[ccc*8+2]), "v"(p[ccc*8+3]));
          asm("v_cvt_pk_bf16_f32 %0, %1, %2" : "=v"(Y0) : "v"(p[ccc*8+4]), "v"(p[ccc*8+5]));
          asm("v_cvt_pk_bf16_f32 %0, %1, %2" : "=v"(Y1) : "v"(p[ccc*8+6]), "v"(p[ccc*8+7]));
          asm volatile("v_permlane32_swap_b32 %0, %1" : "+v"(X0), "+v"(Y0));
          asm volatile("v_permlane32_swap_b32 %0, %1" : "+v"(X1), "+v"(Y1));
          u32x4 dw; dw[0]=X0; dw[1]=X1; dw[2]=Y0; dw[3]=Y1;
          bp[qt*2+ccc] = __builtin_bit_cast(s16x8, dw);
        }
      }
      // PV: accM[i] covers d = i*32..+32 x k = kcol, contraction over this q-tile
      s16x8 av0[4], av1[4];
      #pragma unroll
      for (int c=0;c<4;c++){
        av0[c] = *(s16x8*)&Vs[cur][s][l32][c*16 + hi*8];
        av1[c] = *(s16x8*)&Vs[cur][s][32+l32][c*16 + hi*8];
      }
      #pragma unroll
      for (int c=0;c<4;c++){
        accM0 = mfma32(av0[c], bp[c], accM0);
        accM1 = mfma32(av1[c], bp[c], accM1);
      }
    }
  }
  #pragma unroll
  for (int r2=0;r2<16;r2++){
    const int d0 = 4*hi + (r2&3) + 8*(r2>>2);
    Mt[((long)(b*1024 + h*64 + d0))*2048 + kcol]      = f2bf(accM0[r2]);
    Mt[((long)(b*1024 + h*64 + d0 + 32))*2048 + kcol] = f2bf(accM1[r2]);
  }
}

extern "C" void kernel_launch(void* const* d_in, const int* in_sizes, int n_in,
                              void* d_out, int out_size, void* d_ws, size_t ws_size,
                              hipStream_t stream)
{
  (void)n_in; (void)out_size; (void)ws_size;
  char* ws = (char*)d_ws;
  u32*  dflag = (u32*)ws;            ws += 64;
  u16*  whc   = (u16*)ws;            ws += (size_t)8388608;
  u16*  wqkvc = (u16*)ws;            ws += (size_t)6291456;
  u16*  woc   = (u16*)ws;            ws += (size_t)8388608;
  u16*  bhc   = (u16*)ws;            ws += 4096;
  u16*  bqkvc = (u16*)ws;            ws += 8192;
  u16*  boc   = (u16*)ws;            ws += 4096;
  u16*  xT    = (u16*)ws;            ws += (size_t)8388608;
  u16*  xh    = (u16*)ws;            ws += (size_t)8388608;
  u16*  qkvb  = (u16*)ws;            ws += (size_t)25165824;
  u16*  VtG   = (u16*)ws;            ws += (size_t)8388608;
  u16*  Mt    = (u16*)ws;            ws += (size_t)8388608;
  float* sv   = (float*)ws;          ws += 8192;

  // 0) probe dtype + canonicalize all inputs (weights/biases + x-transpose fused)
  detect_dtype<<<1,256,0,stream>>>((const u16*)d_in[0], dflag);
  CvtArgs ca;
  const void* srcs[10] = {d_in[1], d_in[2], d_in[3], d_in[4], d_in[5],
                          d_in[6], d_in[7], d_in[8], d_in[9], d_in[10]};
  u16* dsts[10] = {whc, bhc, wqkvc, bqkvc, wqkvc+1048576, bqkvc+1024,
                   wqkvc+2097152, bqkvc+2048, woc, boc};
  const int ns[10] = {in_sizes[1], in_sizes[2], in_sizes[3], in_sizes[4], in_sizes[5],
                      in_sizes[6], in_sizes[7], in_sizes[8], in_sizes[9], in_sizes[10]};
  for (int i=0;i<10;i++){ ca.src[i]=srcs[i]; ca.dst[i]=dsts[i]; ca.n[i]=ns[i]; }
  convert_all<<<dim3(2048,11),256,0,stream>>>(ca, d_in[0], dflag, xT);

  const long S2M = 2097152L;   // 2048*1024

  // 1) xh = w_hseq @ xT^T + b_hseq   (NT, row bias)
  gemm_t<64,1,false,false><<<dim3(16,16,2),256,0,stream>>>(whc, xT, bhc, nullptr, dflag, xh,
      2048, 2048, 2048, 1024, 0L, S2M, S2M);

  // 2) qkv = xh @ Wqkv^T + bqkv; q-columns pre-scaled by SCL   (NT, col bias)
  gemm_t<128,2,false,true><<<dim3(16,24,2),256,0,stream>>>(xh, wqkvc, bqkvc, nullptr, dflag, qkvb,
      1024, 1024, 1024, 3072, S2M, 0L, (long)2048*3072);

  // 3) softmax denominators + fused V scale-transpose -> VtG  (R16 dbuf)
  attn_stats<<<dim3(32,32),256,0,stream>>>(qkvb, VtG);

  // 4) Mt = (attn^T @ v)^T   (R17: 128-row staging, 2 sub-tiles/iter)
  attn_pv<<<dim3(16,32),256,0,stream>>>(qkvb, VtG, Mt);

  // 5) sv[b,c] = sum_k Mt[b,c,k]  (softmax rows sum to 1 => = sum_t v[b,t,c])
  rowsum_mt<<<512,256,0,stream>>>(Mt, sv);

  // 6) out = w_oseq @ Mt^T + b_oseq (x) sv   (NT, rank-1 bias, dyn dtype)
  gemm_t<64,3,true,false><<<dim3(16,16,2),256,0,stream>>>(woc, Mt, boc, sv, dflag, d_out,
      2048, 2048, 2048, 1024, 0L, S2M, S2M);
}

// Round 7
// 294.250 us; speedup vs baseline: 1.0880x; 1.0499x over previous
//
#include <hip/hip_runtime.h>
#include <hip/hip_bf16.h>

typedef unsigned short u16;
typedef unsigned int u32;
typedef unsigned long long u64;
typedef __attribute__((ext_vector_type(8))) short s16x8;
typedef __attribute__((ext_vector_type(4))) u32 u32x4;
typedef __attribute__((ext_vector_type(4))) float f32x4;
typedef __attribute__((ext_vector_type(16))) float f32x16;

#define SCL 0.1803368867f   // 0.125 * log2(e): exp(s/8) = 2^(s*SCL)

#if __has_builtin(__builtin_amdgcn_exp2f)
#define EXP2(x) __builtin_amdgcn_exp2f(x)
#else
#define EXP2(x) exp2f(x)
#endif

__device__ __forceinline__ float bf2f(u16 v){ u32 u = ((u32)v)<<16; return __builtin_bit_cast(float,u); }
__device__ __forceinline__ u16 f2bf(float f){
  u32 u = __builtin_bit_cast(u32,f);
  u += 0x7fff + ((u>>16)&1);
  return (u16)(u>>16);
}
__device__ __forceinline__ u32 pkbf(float a, float b){   // pack 2 bf16
  u32 ua = __builtin_bit_cast(u32,a) + 0x8000u;
  u32 ub = __builtin_bit_cast(u32,b) + 0x8000u;
  return (ua>>16) | (ub & 0xFFFF0000u);
}
// async global->LDS, 16B per lane; lds_u MUST be wave-uniform (HW adds lane*16)
__device__ __forceinline__ void glds16(const u16* g, const u16* lds_u){
  __builtin_amdgcn_global_load_lds(
      (const __attribute__((address_space(1))) void*)(u64)g,
      (__attribute__((address_space(3))) void*)(u32)(u64)lds_u,
      16, 0, 0);
}
__device__ __forceinline__ f32x4 mfma16(s16x8 a, s16x8 b, f32x4 c){
  return __builtin_amdgcn_mfma_f32_16x16x32_bf16(a,b,c,0,0,0);
}
__device__ __forceinline__ f32x16 mfma32(s16x8 a, s16x8 b, f32x16 c){
  return __builtin_amdgcn_mfma_f32_32x32x16_bf16(a,b,c,0,0,0);
}

// ---------------------------------------------------------------------------
// dtype probe (validated rounds 2-11)
// ---------------------------------------------------------------------------
__global__ __launch_bounds__(256) void detect_dtype(const u16* __restrict__ x, u32* __restrict__ flag){
  __shared__ int cnt;
  if (threadIdx.x==0) cnt = 0;
  __syncthreads();
  int local = 0;
  for (int i = threadIdx.x; i < 4096; i += 256){
    u16 v = x[2*i];
    int e = (v>>7)&0xFF;
    if (e >= 140 || e <= 100) local++;
  }
  atomicAdd(&cnt, local);
  __syncthreads();
  if (threadIdx.x==0) *flag = (cnt > 1024) ? 1u : 0u;
}

struct CvtArgs { const void* src[10]; u16* dst[10]; int n[10]; };

// ---------------------------------------------------------------------------
// Merged weight/bias convert (y<10) + x convert-transpose (y==10).
// Grid (2048, 11), block 256.
// ---------------------------------------------------------------------------
__global__ __launch_bounds__(256) void convert_all(
    CvtArgs a, const void* __restrict__ xsrc,
    const u32* __restrict__ flag, u16* __restrict__ xT)
{
  __shared__ u16 T[64][72];
  const int t = threadIdx.x;
  if (blockIdx.y < 10){
    const int which = blockIdx.y;
    const int n = a.n[which];
    const int base = blockIdx.x*2048 + t;
    if (base >= n) return;
    u16* dst = a.dst[which];
    if (*flag){
      const float* s = (const float*)a.src[which];
      #pragma unroll
      for (int j=0;j<8;j++){ int i = base + j*256; if (i<n) dst[i] = f2bf(s[i]); }
    } else {
      const u16* s = (const u16*)a.src[which];
      #pragma unroll
      for (int j=0;j<8;j++){ int i = base + j*256; if (i<n) dst[i] = s[i]; }
    }
    return;
  }
  // ---- x transpose: xT[b][c][s] = cvt(x[b][s][c]) ----
  const int bx = blockIdx.x;
  if (bx >= 1024) return;
  const int s0 = (bx&31)*64, c0 = ((bx>>5)&15)*64, b = bx>>9;
  const int r = t>>2, cc = (t&3)*16;
  const long off = ((long)(b*2048 + s0 + r))*1024 + c0 + cc;
  if (*flag){
    const float* p = (const float*)xsrc + off;
    #pragma unroll
    for (int j=0;j<16;j++) T[r][cc+j] = f2bf(p[j]);
  } else {
    const u16* p = (const u16*)xsrc + off;
    *(s16x8*)&T[r][cc]   = *(const s16x8*)p;
    *(s16x8*)&T[r][cc+8] = *(const s16x8*)(p+8);
  }
  __syncthreads();
  {
    const int orow = t&63, oc = (t>>6)*16;
    u16 tmp[16];
    #pragma unroll
    for (int j=0;j<16;j++) tmp[j] = T[oc+j][orow];
    u16* q = xT + (long)b*2097152 + (long)(c0+orow)*2048 + s0 + oc;
    *(s16x8*)q     = *(s16x8*)&tmp[0];
    *(s16x8*)(q+8) = *(s16x8*)&tmp[8];
  }
}

// ---------------------------------------------------------------------------
// sv[row] = sum_k Mt[row][k]  (softmax rows sum to 1 => equals sum_t v[b,t,c]).
// Grid 512, block 256 (4 waves, 1 Mt-row each).
// ---------------------------------------------------------------------------
__global__ __launch_bounds__(256) void rowsum_mt(const u16* __restrict__ Mt, float* __restrict__ sv){
  const int row = blockIdx.x*4 + (threadIdx.x>>6);
  const int lane = threadIdx.x&63;
  const u16* p = Mt + (long)row*2048;
  float s = 0.f;
  #pragma unroll
  for (int i=0;i<4;i++){
    s16x8 v = *(const s16x8*)&p[i*512 + lane*8];
    #pragma unroll
    for (int j=0;j<8;j++) s += bf2f((u16)v[j]);
  }
  #pragma unroll
  for (int off=32; off>=1; off>>=1) s += __shfl_xor(s, off);
  if (lane==0) sv[row] = s;
}

// ---------------------------------------------------------------------------
// NT GEMM, BM=128 x BN tile, BK=32, double-buffered LDS + global_load_lds(16B).
// (round-5/7 version — proven)
// ---------------------------------------------------------------------------
template<int BN, int BMODE, bool DYN, bool QS>
__global__ __launch_bounds__(256) void gemm_t(
    const u16* __restrict__ A, const u16* __restrict__ B,
    const u16* __restrict__ bias, const float* __restrict__ r1col,
    const u32* __restrict__ dflag, void* __restrict__ C,
    int K, int lda, int ldb, int ldc,
    long aBatch, long bBatch, long cBatch)
{
  constexpr int BM = 128;
  constexpr int ACH = BM/64, BCH = BN/64;
  constexpr int MI = (BN==128) ? 4 : 2;
  __shared__ u16 As[2][BM*32];
  __shared__ u16 Bs[2][BN*32];
  const int t = threadIdx.x, w = t>>6, quad = (t&63)>>4, l16 = t&15;
  const int z = blockIdx.z;
  const int m0 = blockIdx.x*BM, n0 = blockIdx.y*BN;
  const u16* Ag = A + (long)z*aBatch + (long)m0*lda;
  const u16* Bg = B + (long)z*bBatch + (long)n0*ldb;
  const int wm = (BN==128) ? (w>>1)*64 : w*32;
  const int wn = (BN==128) ? (w&1)*64 : 0;

  auto stage = [&](int buf, int k0){
    #pragma unroll
    for (int i=0;i<ACH;i++){
      const int chunk = i*256 + t;
      glds16(Ag + (long)(chunk>>2)*lda + k0 + (chunk&3)*8, &As[buf][(i*256 + w*64)*8]);
    }
    #pragma unroll
    for (int i=0;i<BCH;i++){
      const int chunk = i*256 + t;
      glds16(Bg + (long)(chunk>>2)*ldb + k0 + (chunk&3)*8, &Bs[buf][(i*256 + w*64)*8]);
    }
  };

  f32x4 acc[MI][4];
  #pragma unroll
  for (int i=0;i<MI;i++)
    #pragma unroll
    for (int j=0;j<4;j++) acc[i][j] = (f32x4){0.f,0.f,0.f,0.f};

  stage(0, 0);
  const int nk = K>>5;
  for (int kt=0; kt<nk; ++kt){
    __syncthreads();
    if (kt+1 < nk) stage((kt+1)&1, (kt+1)<<5);
    const u16* as = As[kt&1];
    const u16* bs = Bs[kt&1];
    s16x8 a[MI], bb[4];
    #pragma unroll
    for (int i=0;i<MI;i++) a[i] = *(const s16x8*)&as[(wm + i*16 + l16)*32 + quad*8];
    #pragma unroll
    for (int j=0;j<4;j++)  bb[j]= *(const s16x8*)&bs[(wn + j*16 + l16)*32 + quad*8];
    #pragma unroll
    for (int i=0;i<MI;i++)
      #pragma unroll
      for (int j=0;j<4;j++)
        acc[i][j] = mfma16(a[i], bb[j], acc[i][j]);
  }

  bool f32o = false;
  if (DYN) f32o = (*dflag != 0);
  #pragma unroll
  for (int i=0;i<MI;i++){
    #pragma unroll
    for (int j=0;j<4;j++){
      const int col = n0 + wn + j*16 + l16;
      #pragma unroll
      for (int r=0;r<4;r++){
        const int row = m0 + wm + i*16 + quad*4 + r;
        float vv = acc[i][j][r];
        if (BMODE==1) vv += bf2f(bias[row]);
        if (BMODE==2) vv += bf2f(bias[col]);
        if (BMODE==3) vv += bf2f(bias[row]) * r1col[z*1024 + col];
        if (QS){ if (col < 1024) vv *= SCL; }
        const long idx = (long)z*cBatch + (long)row*ldc + col;
        if (DYN && f32o) ((float*)C)[idx] = vv;
        else             ((u16*)C)[idx]   = f2bf(vv);
      }
    }
  }
}

// ---------------------------------------------------------------------------
// Fused softmax-denominator + V-scale-transpose (R16 dbuf + T5 setprio).
// ---------------------------------------------------------------------------
__global__ __launch_bounds__(256) void attn_stats(const u16* __restrict__ qkv, u16* __restrict__ VtG){
  __shared__ u16 Qs[64][68];
  __shared__ u16 Ks[2][64][68];
  __shared__ float red[2][64];
  __shared__ float ilv[64];
  const int q0 = blockIdx.x*64, bh = blockIdx.y, b = bh>>4, h = bh&15;
  const int t = threadIdx.x, w = t>>6, l32 = t&31, half = (t&63)>>5;
  const int wq = w>>1, wk = w&1;
  const int r = t>>2, cc = (t&3)*16;
  {
    const u16* p = &qkv[((long)(b*2048 + q0 + r))*3072 + h*64 + cc];
    *(s16x8*)&Qs[r][cc]   = *(const s16x8*)p;
    *(s16x8*)&Qs[r][cc+8] = *(const s16x8*)(p+8);
  }
  const u16* kg = &qkv[((long)(b*2048 + r))*3072 + 1024 + h*64 + cc];
  // tile0 -> regs -> Ks[0]; prefetch tile1 into regs
  s16x8 sk0 = *(const s16x8*)kg;
  s16x8 sk1 = *(const s16x8*)(kg+8);
  *(s16x8*)&Ks[0][r][cc]   = sk0;
  *(s16x8*)&Ks[0][r][cc+8] = sk1;
  sk0 = *(const s16x8*)(kg + (long)64*3072);
  sk1 = *(const s16x8*)(kg + (long)64*3072 + 8);
  __syncthreads();                     // Qs + Ks[0] visible
  s16x8 aq[4];
  #pragma unroll
  for (int u=0;u<4;u++) aq[u] = *(s16x8*)&Qs[wq*32 + l32][u*16 + half*8];
  float lp[16];
  #pragma unroll
  for (int r2=0;r2<16;r2++) lp[r2] = 0.f;

  for (int kc=0; kc<32; ++kc){
    __syncthreads();                   // Ks[cur] writes visible; prev reads of Ks[cur^1] done
    const int cur = kc&1;
    if (kc+1 < 32){
      *(s16x8*)&Ks[cur^1][r][cc]   = sk0;
      *(s16x8*)&Ks[cur^1][r][cc+8] = sk1;
      if (kc+2 < 32){
        sk0 = *(const s16x8*)(kg + (long)(kc+2)*64*3072);
        sk1 = *(const s16x8*)(kg + (long)(kc+2)*64*3072 + 8);
      }
    }
    s16x8 kb[4];
    #pragma unroll
    for (int u=0;u<4;u++) kb[u] = *(s16x8*)&Ks[cur][wk*32 + l32][u*16 + half*8];
    f32x16 acc = {};
    __builtin_amdgcn_s_setprio(1);
    #pragma unroll
    for (int u=0;u<4;u++) acc = mfma32(aq[u], kb[u], acc);
    __builtin_amdgcn_s_setprio(0);
    #pragma unroll
    for (int r2=0;r2<16;r2++) lp[r2] += EXP2(acc[r2]);
  }
  #pragma unroll
  for (int off=1; off<32; off<<=1)
    #pragma unroll
    for (int r2=0;r2<16;r2++) lp[r2] += __shfl_xor(lp[r2], off);
  if (l32 == 0){
    #pragma unroll
    for (int r2=0;r2<16;r2++)
      red[wk][wq*32 + 4*half + (r2&3) + 8*(r2>>2)] = lp[r2];
  }
  __syncthreads();
  if (t < 64) ilv[t] = 1.f / (red[0][t] + red[1][t]);
  __syncthreads();
  // ---- fused V scale+transpose through Qs (dead after aq) ----
  {
    const u16* p = &qkv[((long)(b*2048 + q0 + r))*3072 + 2048 + h*64 + cc];
    const float sc = ilv[r];
    s16x8 v0 = *(const s16x8*)p, v1 = *(const s16x8*)(p+8);
    #pragma unroll
    for (int j=0;j<8;j++){
      Qs[r][cc+j]   = f2bf(bf2f((u16)v0[j])*sc);
      Qs[r][cc+8+j] = f2bf(bf2f((u16)v1[j])*sc);
    }
  }
  __syncthreads();
  {
    const int orow = t&63, oc = (t>>6)*16;
    u16 tmp[16];
    #pragma unroll
    for (int j=0;j<16;j++) tmp[j] = Qs[oc+j][orow];
    u16* q = VtG + (long)b*2097152 + (long)(h*64+orow)*2048 + q0 + oc;
    *(s16x8*)q     = *(s16x8*)&tmp[0];
    *(s16x8*)(q+8) = *(s16x8*)&tmp[8];
  }
}

// ---------------------------------------------------------------------------
// Mt[b, h*64+d, k] = sum_q exp2(q'.k) * vtilde[d,q]   (V pre-scaled by il[q]).
// R18: R16 structure (proven 48 us) widened to 512 threads / 8 waves /
// 256 kcols per block. One block's Q/V staging now serves 256 kcols:
// per-thread staging halves (1x16B Q + 1x16B V per iter), L2 Q/V re-read
// traffic halves. Same single-barrier dbuf + T14 reg-prefetch + wave-private
// P via permlane32_swap (R13-verified) + cvt_pk pack (R15) + T5 setprio.
// Grid (8,32) = 256 blocks = 1/CU, 8 waves = 2/SIMD.  LDS 34.8 KB.
// ---------------------------------------------------------------------------
__global__ __launch_bounds__(512,2) void attn_pv(
    const u16* __restrict__ qkv, const u16* __restrict__ VtG, u16* __restrict__ Mt)
{
  __shared__ u16 Qs[2][64][68];
  __shared__ u16 Vs[2][64][68];
  const int t = threadIdx.x, w = t>>6, l32 = t&31, hi = (t&63)>>5;
  const int bh = blockIdx.y, b = bh>>4, h = bh&15;
  const int kcol = blockIdx.x*256 + w*32 + l32;
  const int r = t>>3, cc = (t&7)*8;

  // K fragments (B-op of QK): lane holds K[kcol][d = c*16 + hi*8 + j].
  // One-time uncoalesced global load (L2-cached), persistent in regs.
  const u16* kp = qkv + ((long)(b*2048 + kcol))*3072 + 1024 + h*64 + hi*8;
  s16x8 kb[4];
  #pragma unroll
  for (int c=0;c<4;c++) kb[c] = *(const s16x8*)(kp + c*16);

  // coalesced staging pointers: thread loads row r, cols cc..cc+7 (16B)
  const u16* qg = &qkv[((long)(b*2048 + r))*3072 + h*64 + cc];
  const u16* vg = &VtG[((long)(b*1024 + h*64 + r))*2048 + cc];

  // tile0 -> regs -> buf0; prefetch tile1 into regs
  s16x8 sq = *(const s16x8*)qg;
  s16x8 sv = *(const s16x8*)vg;
  *(s16x8*)&Qs[0][r][cc] = sq;
  *(s16x8*)&Vs[0][r][cc] = sv;
  sq = *(const s16x8*)(qg + (long)64*3072);
  sv = *(const s16x8*)(vg + 64);

  f32x16 accM0 = {}, accM1 = {};
  for (int i=0; i<32; ++i){
    __syncthreads();                 // buf[cur] writes visible; prev reads of buf[cur^1] done
    const int cur = i&1;
    if (i+1 < 32){                   // write tile i+1 (overlaps with compute below)
      *(s16x8*)&Qs[cur^1][r][cc] = sq;
      *(s16x8*)&Vs[cur^1][r][cc] = sv;
      if (i+2 < 32){                 // T14: issue tile i+2 loads (2-iteration cover)
        sq = *(const s16x8*)(qg + (long)(i+2)*64*3072);
        sv = *(const s16x8*)(vg + (i+2)*64);
      }
    }
    // fragments from buf[cur] (per wave: full 64-q range, own 32 kcols)
    s16x8 aq0[4], aq1[4];
    #pragma unroll
    for (int c=0;c<4;c++){
      aq0[c] = *(s16x8*)&Qs[cur][l32][c*16 + hi*8];
      aq1[c] = *(s16x8*)&Qs[cur][32+l32][c*16 + hi*8];
    }
    f32x16 acc0 = {}, acc1 = {};
    __builtin_amdgcn_s_setprio(1);
    #pragma unroll
    for (int c=0;c<4;c++){
      acc0 = mfma32(aq0[c], kb[c], acc0);
      acc1 = mfma32(aq1[c], kb[c], acc1);
    }
    __builtin_amdgcn_s_setprio(0);
    // exp -> cvt_pk_bf16 -> permlane32_swap: PV B-fragments in-register
    // (R13-verified layout). C/D: lane holds P[q = qt*32 + (r&3)+8*(r>>2)+4*hi][kcol];
    // B-frag bp[c] needs P[q = c*16 + 8*hi + j][kcol].
    s16x8 bp[4];
    #pragma unroll
    for (int qt=0;qt<2;qt++){
      float p[16];
      #pragma unroll
      for (int r2=0;r2<16;r2++) p[r2] = EXP2(qt ? acc1[r2] : acc0[r2]);
      #pragma unroll
      for (int ccc=0; ccc<2; ccc++){
        u32 X0, X1, Y0, Y1;
        asm("v_cvt_pk_bf16_f32 %0, %1, %2" : "=v"(X0) : "v"(p[ccc*8+0]), "v"(p[ccc*8+1]));
        asm("v_cvt_pk_bf16_f32 %0, %1, %2" : "=v"(X1) : "v"(p[ccc*8+2]), "v"(p[ccc*8+3]));
        asm("v_cvt_pk_bf16_f32 %0, %1, %2" : "=v"(Y0) : "v"(p[ccc*8+4]), "v"(p[ccc*8+5]));
        asm("v_cvt_pk_bf16_f32 %0, %1, %2" : "=v"(Y1) : "v"(p[ccc*8+6]), "v"(p[ccc*8+7]));
        asm volatile("v_permlane32_swap_b32 %0, %1" : "+v"(X0), "+v"(Y0));
        asm volatile("v_permlane32_swap_b32 %0, %1" : "+v"(X1), "+v"(Y1));
        u32x4 dw; dw[0]=X0; dw[1]=X1; dw[2]=Y0; dw[3]=Y1;
        bp[qt*2+ccc] = __builtin_bit_cast(s16x8, dw);
      }
    }
    // PV: accM[i] covers d = i*32..+32 x k = kcol, contraction over this q-tile
    s16x8 av0[4], av1[4];
    #pragma unroll
    for (int c=0;c<4;c++){
      av0[c] = *(s16x8*)&Vs[cur][l32][c*16 + hi*8];
      av1[c] = *(s16x8*)&Vs[cur][32+l32][c*16 + hi*8];
    }
    __builtin_amdgcn_s_setprio(1);
    #pragma unroll
    for (int c=0;c<4;c++){
      accM0 = mfma32(av0[c], bp[c], accM0);
      accM1 = mfma32(av1[c], bp[c], accM1);
    }
    __builtin_amdgcn_s_setprio(0);
  }
  #pragma unroll
  for (int r2=0;r2<16;r2++){
    const int d0 = 4*hi + (r2&3) + 8*(r2>>2);
    Mt[((long)(b*1024 + h*64 + d0))*2048 + kcol]      = f2bf(accM0[r2]);
    Mt[((long)(b*1024 + h*64 + d0 + 32))*2048 + kcol] = f2bf(accM1[r2]);
  }
}

extern "C" void kernel_launch(void* const* d_in, const int* in_sizes, int n_in,
                              void* d_out, int out_size, void* d_ws, size_t ws_size,
                              hipStream_t stream)
{
  (void)n_in; (void)out_size; (void)ws_size;
  char* ws = (char*)d_ws;
  u32*  dflag = (u32*)ws;            ws += 64;
  u16*  whc   = (u16*)ws;            ws += (size_t)8388608;
  u16*  wqkvc = (u16*)ws;            ws += (size_t)6291456;
  u16*  woc   = (u16*)ws;            ws += (size_t)8388608;
  u16*  bhc   = (u16*)ws;            ws += 4096;
  u16*  bqkvc = (u16*)ws;            ws += 8192;
  u16*  boc   = (u16*)ws;            ws += 4096;
  u16*  xT    = (u16*)ws;            ws += (size_t)8388608;
  u16*  xh    = (u16*)ws;            ws += (size_t)8388608;
  u16*  qkvb  = (u16*)ws;            ws += (size_t)25165824;
  u16*  VtG   = (u16*)ws;            ws += (size_t)8388608;
  u16*  Mt    = (u16*)ws;            ws += (size_t)8388608;
  float* sv   = (float*)ws;          ws += 8192;

  // 0) probe dtype + canonicalize all inputs (weights/biases + x-transpose fused)
  detect_dtype<<<1,256,0,stream>>>((const u16*)d_in[0], dflag);
  CvtArgs ca;
  const void* srcs[10] = {d_in[1], d_in[2], d_in[3], d_in[4], d_in[5],
                          d_in[6], d_in[7], d_in[8], d_in[9], d_in[10]};
  u16* dsts[10] = {whc, bhc, wqkvc, bqkvc, wqkvc+1048576, bqkvc+1024,
                   wqkvc+2097152, bqkvc+2048, woc, boc};
  const int ns[10] = {in_sizes[1], in_sizes[2], in_sizes[3], in_sizes[4], in_sizes[5],
                      in_sizes[6], in_sizes[7], in_sizes[8], in_sizes[9], in_sizes[10]};
  for (int i=0;i<10;i++){ ca.src[i]=srcs[i]; ca.dst[i]=dsts[i]; ca.n[i]=ns[i]; }
  convert_all<<<dim3(2048,11),256,0,stream>>>(ca, d_in[0], dflag, xT);

  const long S2M = 2097152L;   // 2048*1024

  // 1) xh = w_hseq @ xT^T + b_hseq   (NT, row bias)
  gemm_t<64,1,false,false><<<dim3(16,16,2),256,0,stream>>>(whc, xT, bhc, nullptr, dflag, xh,
      2048, 2048, 2048, 1024, 0L, S2M, S2M);

  // 2) qkv = xh @ Wqkv^T + bqkv; q-columns pre-scaled by SCL   (NT, col bias)
  gemm_t<128,2,false,true><<<dim3(16,24,2),256,0,stream>>>(xh, wqkvc, bqkvc, nullptr, dflag, qkvb,
      1024, 1024, 1024, 3072, S2M, 0L, (long)2048*3072);

  // 3) softmax denominators + fused V scale-transpose -> VtG  (R16 dbuf + setprio)
  attn_stats<<<dim3(32,32),256,0,stream>>>(qkvb, VtG);

  // 4) Mt = (attn^T @ v)^T   (R18: 512-thread, 256 kcols/block, setprio)
  attn_pv<<<dim3(8,32),512,0,stream>>>(qkvb, VtG, Mt);

  // 5) sv[b,c] = sum_k Mt[b,c,k]  (softmax rows sum to 1 => = sum_t v[b,t,c])
  rowsum_mt<<<512,256,0,stream>>>(Mt, sv);

  // 6) out = w_oseq @ Mt^T + b_oseq (x) sv   (NT, rank-1 bias, dyn dtype)
  gemm_t<64,3,true,false><<<dim3(16,16,2),256,0,stream>>>(woc, Mt, boc, sv, dflag, d_out,
      2048, 2048, 2048, 1024, 0L, S2M, S2M);
}